// Round 12
// baseline (337.997 us; speedup 1.0000x reference)
//
#include <hip/hip_runtime.h>

#define FI 256
#define FH 64
#define FO 128
#define ASORT_CHUNK 2048
// ushort-view row stride 256: bf16 h1 at ushort[128..191], bf16 hrelu at [192..255],
// fp32 combined at float[0..63].

typedef __attribute__((ext_vector_type(8))) short bf16x8;
typedef __attribute__((ext_vector_type(4))) float f32x4;

__device__ __forceinline__ ushort f2bf(float x) {   // fp32 -> bf16 RNE
    unsigned b = __float_as_uint(x);
    b += 0x7fffu + ((b >> 16) & 1u);
    return (ushort)(b >> 16);
}
__device__ __forceinline__ float bf2f(ushort u) {
    return __uint_as_float(((unsigned)u) << 16);
}

// ---------------- small kernels ----------------

__global__ void zero_i32(int* __restrict__ p, int n) {
    int i = blockIdx.x * 256 + threadIdx.x;
    if (i < n) p[i] = 0;
}

__global__ void deg_cnt_kernel(const int* __restrict__ dst, int* __restrict__ cnt, int E) {
    int base = blockIdx.x * 1024 + threadIdx.x;
    #pragma unroll
    for (int q = 0; q < 4; ++q) {
        int e = base + q * 256;
        if (e < E) atomicAdd(&cnt[dst[e]], 1);
    }
}

__global__ void dinv_kernel(const int* __restrict__ cnt, float* __restrict__ dinv, int N) {
    int i = blockIdx.x * 256 + threadIdx.x;
    if (i < N) dinv[i] = rsqrtf((float)cnt[i] + 1.0f);
}

// ---------------- CSR build: bucketed histogram + binned counting sort ----------------

// hist (blocks < nblkA) + W1 fragment prep (16 trailing blocks; no extra launch).
// Frag layout entry e=(c*8+t)*64+l: col=c*16+(l&15), k=t*32+(l>>4)*8+j (validated r8/r9).
__global__ __launch_bounds__(256) void hist_wprep_kernel(const int* __restrict__ dst,
                                                         int* __restrict__ bucket_cnt,
                                                         const float* __restrict__ W1,
                                                         short* __restrict__ WH,
                                                         short* __restrict__ WL,
                                                         int E, int nblkA) {
    if ((int)blockIdx.x >= nblkA) {
        int f = ((int)blockIdx.x - nblkA) * 256 + threadIdx.x;   // float4 idx in 256x64 W1
        float4 wv = *(const float4*)&W1[(size_t)f * 4];
        int k  = f >> 4;
        int c4 = f & 15;
        int j  = k & 7;
        int e0 = ((c4 >> 2) * 8 + (k >> 5)) * 64 + ((k >> 3) & 3) * 16 + (c4 & 3) * 4;
        float vv[4] = {wv.x, wv.y, wv.z, wv.w};
        #pragma unroll
        for (int cc = 0; cc < 4; ++cc) {
            ushort h = f2bf(vv[cc]);
            WH[(e0 + cc) * 8 + j] = (short)h;
            WL[(e0 + cc) * 8 + j] = (short)f2bf(vv[cc] - bf2f(h));
        }
        return;
    }
    __shared__ int lcnt[256];
    int t = threadIdx.x;
    int base = blockIdx.x * ASORT_CHUNK;
    lcnt[t] = 0;
    __syncthreads();
    #pragma unroll
    for (int j = 0; j < 8; ++j) {
        int e = base + j * 256 + t;
        if (e < E) atomicAdd(&lcnt[((unsigned)dst[e]) >> 8], 1);
    }
    __syncthreads();
    int v = lcnt[t];
    if (v > 0) atomicAdd(&bucket_cnt[t], v);
}

__global__ __launch_bounds__(256) void bucket_scan_kernel(const int* __restrict__ bucket_cnt,
                                                          int* __restrict__ bucket_base,
                                                          int* __restrict__ bucket_pos, int E) {
    __shared__ int sc[256];
    int t = threadIdx.x;
    int sum = bucket_cnt[t];
    sc[t] = sum;
    __syncthreads();
    for (int off = 1; off < 256; off <<= 1) {
        int u = (t >= off) ? sc[t - off] : 0;
        __syncthreads();
        sc[t] += u;
        __syncthreads();
    }
    int excl = sc[t] - sum;
    bucket_base[t] = excl;
    bucket_pos[t]  = excl;
    if (t == 255) bucket_base[256] = sc[255];   // == E
}

// Pass A: per-block LDS counting sort by bucket (dst>>8), flushed as contiguous runs.
__global__ __launch_bounds__(256) void binA_kernel(const int* __restrict__ src,
                                                   const int* __restrict__ dst,
                                                   int* __restrict__ bucket_pos,
                                                   unsigned* __restrict__ binned, int E) {
    __shared__ int lcnt[256];
    __shared__ int lbase[256];
    __shared__ int gbase[256];
    __shared__ int sc[256];
    __shared__ unsigned sorted[ASORT_CHUNK];
    int t = threadIdx.x;
    int base = blockIdx.x * ASORT_CHUNK;
    lcnt[t] = 0;
    __syncthreads();
    unsigned pk[8];
    short bb[8];
    short mi[8];
    #pragma unroll
    for (int j = 0; j < 8; ++j) {
        int e = base + j * 256 + t;
        if (e < E) {
            unsigned s = (unsigned)src[e];
            unsigned d = (unsigned)dst[e];
            pk[j] = s | (d << 16);
            int b = (int)(d >> 8);
            bb[j] = (short)b;
            mi[j] = (short)atomicAdd(&lcnt[b], 1);
        } else {
            bb[j] = -1;
        }
    }
    __syncthreads();
    int v = lcnt[t];
    sc[t] = v;
    __syncthreads();
    #pragma unroll
    for (int off = 1; off < 256; off <<= 1) {
        int u = (t >= off) ? sc[t - off] : 0;
        __syncthreads();
        sc[t] += u;
        __syncthreads();
    }
    lbase[t] = sc[t] - v;                       // exclusive prefix
    if (v > 0) gbase[t] = atomicAdd(&bucket_pos[t], v);
    __syncthreads();
    #pragma unroll
    for (int j = 0; j < 8; ++j)
        if (bb[j] >= 0) sorted[lbase[(int)bb[j]] + (int)mi[j]] = pk[j];
    int tot = sc[255];
    __syncthreads();
    for (int i = t; i < tot; i += 256) {
        unsigned vv = sorted[i];
        int b = (int)(vv >> 24);                // dst>>8 (dst < 65536)
        binned[gbase[b] + (i - lbase[b])] = vv;
    }
}

// Pass B: one block per bucket; per-node histogram+scan in LDS, writes row_start/cnt/dinv,
// then scatters rec4 (src-only) inside the bucket's ~32KB region.
__global__ __launch_bounds__(256) void binB_kernel(const int* __restrict__ bucket_base,
                                                   const unsigned* __restrict__ binned,
                                                   int* __restrict__ rec4,
                                                   int* __restrict__ row_start,
                                                   int* __restrict__ cnt,
                                                   float* __restrict__ dinv, int N) {
    __shared__ int lcnt[256];
    __shared__ int sc[256];
    __shared__ int lstart[256];
    __shared__ int loff[256];
    int t = threadIdx.x;
    int d0 = blockIdx.x << 8;
    int start = bucket_base[blockIdx.x];
    int end   = bucket_base[blockIdx.x + 1];
    lcnt[t] = 0;
    __syncthreads();
    for (int i = start + t; i < end; i += 256)
        atomicAdd(&lcnt[(binned[i] >> 16) & 0xffu], 1);
    __syncthreads();
    int v = lcnt[t];
    sc[t] = v;
    __syncthreads();
    for (int off = 1; off < 256; off <<= 1) {
        int u = (t >= off) ? sc[t - off] : 0;
        __syncthreads();
        sc[t] += u;
        __syncthreads();
    }
    int st = start + sc[t] - v;                  // row start for node d0+t
    lstart[t] = st;
    loff[t] = 0;
    if (d0 + t < N) {
        row_start[d0 + t] = st;
        cnt[d0 + t] = v;
        dinv[d0 + t] = rsqrtf((float)v + 1.0f);
    }
    __syncthreads();
    int i = start + t;
    for (; i + 768 < end; i += 1024) {
        unsigned v0 = binned[i];
        unsigned v1 = binned[i + 256];
        unsigned v2 = binned[i + 512];
        unsigned v3 = binned[i + 768];
        int dA = (int)((v0 >> 16) & 0xffu); int kA = atomicAdd(&loff[dA], 1);
        rec4[lstart[dA] + kA] = (int)(v0 & 0xffffu);
        int dB = (int)((v1 >> 16) & 0xffu); int kB = atomicAdd(&loff[dB], 1);
        rec4[lstart[dB] + kB] = (int)(v1 & 0xffffu);
        int dC = (int)((v2 >> 16) & 0xffu); int kC = atomicAdd(&loff[dC], 1);
        rec4[lstart[dC] + kC] = (int)(v2 & 0xffffu);
        int dD = (int)((v3 >> 16) & 0xffu); int kD = atomicAdd(&loff[dD], 1);
        rec4[lstart[dD] + kD] = (int)(v3 & 0xffffu);
    }
    for (; i < end; i += 256) {
        unsigned v4 = binned[i];
        int d = (int)((v4 >> 16) & 0xffu);
        int k = atomicAdd(&loff[d], 1);
        rec4[lstart[d] + k] = (int)(v4 & 0xffffu);
    }
}

// ---------------- gather-side aggregation, v3 ----------------
// Wave = 1 node. Lane L: g = L>>3 (8 edge slots), q = L&7 (8 bf16 = 16B per lane).
// Per 64-edge chunk: cooperative (src,w) preload + shfl broadcast; loads and FMA in
// two statically-indexed unrolled loops -> up to 8 gathers in flight per wave.

#define ACC8(hv, wt)                                                   \
    acc[0] = fmaf(__uint_as_float((hv).x << 16),         wt, acc[0]);  \
    acc[1] = fmaf(__uint_as_float((hv).x & 0xffff0000u), wt, acc[1]);  \
    acc[2] = fmaf(__uint_as_float((hv).y << 16),         wt, acc[2]);  \
    acc[3] = fmaf(__uint_as_float((hv).y & 0xffff0000u), wt, acc[3]);  \
    acc[4] = fmaf(__uint_as_float((hv).z << 16),         wt, acc[4]);  \
    acc[5] = fmaf(__uint_as_float((hv).z & 0xffff0000u), wt, acc[5]);  \
    acc[6] = fmaf(__uint_as_float((hv).w << 16),         wt, acc[6]);  \
    acc[7] = fmaf(__uint_as_float((hv).w & 0xffff0000u), wt, acc[7]);

#define GATHER_CHUNK(OFFS)                                                     \
    for (int c0 = 0; c0 < n; c0 += 64) {                                       \
        int idx_l = c0 + L;                                                    \
        int sreg = node;                                                       \
        float wreg = 0.f;                                                      \
        if (idx_l < n) {                                                       \
            sreg = rec4[beg + idx_l];                                          \
            wreg = dinv[sreg] * dvd;                                           \
        }                                                                      \
        int m = n - c0; if (m > 64) m = 64;                                    \
        int umax = (m + 7) >> 3;                                               \
        uint4 hv[8];                                                           \
        _Pragma("unroll")                                                      \
        for (int u = 0; u < 8; ++u) {                                          \
            if (u < umax) {                                                    \
                int sidx = __shfl(sreg, u * 8 + g, 64);                        \
                hv[u] = *(const uint4*)(hb + (size_t)sidx * 256 + (OFFS) + q * 8); \
            }                                                                  \
        }                                                                      \
        _Pragma("unroll")                                                      \
        for (int u = 0; u < 8; ++u) {                                          \
            if (u < umax) {                                                    \
                float wt = __shfl(wreg, u * 8 + g, 64);                        \
                ACC8(hv[u], wt)                                                \
            }                                                                  \
        }                                                                      \
    }

// layer 1: gather bf16 h1 (ushort cols [128..191]); write bf16 hrelu = relu(acc + dv^2*own + b1)
__global__ void gather_relu_kernel(const int* __restrict__ rec4, const int* __restrict__ row_start,
                                   const int* __restrict__ cnt, const float* __restrict__ dinv,
                                   const float* __restrict__ b1, float* __restrict__ out, int N) {
    int node = blockIdx.x * 4 + (threadIdx.x >> 6);
    if (node >= N) return;
    int L = threadIdx.x & 63;
    int g = L >> 3;
    int q = L & 7;
    const ushort* hb = (const ushort*)out;
    int beg = row_start[node];
    int n   = cnt[node];
    float dvd = dinv[node];
    float acc[8] = {0.f, 0.f, 0.f, 0.f, 0.f, 0.f, 0.f, 0.f};
    GATHER_CHUNK(128)
    #pragma unroll
    for (int off = 8; off < 64; off <<= 1)
        #pragma unroll
        for (int j = 0; j < 8; ++j)
            acc[j] += __shfl_xor(acc[j], off, 64);
    if (L < 8) {
        float dv2 = dvd * dvd;
        uint4 ho = *(const uint4*)(hb + (size_t)node * 256 + 128 + q * 8);
        float4 bl = *(const float4*)&b1[q * 8];
        float4 bh = *(const float4*)&b1[q * 8 + 4];
        float r0 = fmaxf(acc[0] + dv2 * __uint_as_float(ho.x << 16)         + bl.x, 0.f);
        float r1 = fmaxf(acc[1] + dv2 * __uint_as_float(ho.x & 0xffff0000u) + bl.y, 0.f);
        float r2 = fmaxf(acc[2] + dv2 * __uint_as_float(ho.y << 16)         + bl.z, 0.f);
        float r3 = fmaxf(acc[3] + dv2 * __uint_as_float(ho.y & 0xffff0000u) + bl.w, 0.f);
        float r4 = fmaxf(acc[4] + dv2 * __uint_as_float(ho.z << 16)         + bh.x, 0.f);
        float r5 = fmaxf(acc[5] + dv2 * __uint_as_float(ho.z & 0xffff0000u) + bh.y, 0.f);
        float r6 = fmaxf(acc[6] + dv2 * __uint_as_float(ho.w << 16)         + bh.z, 0.f);
        float r7 = fmaxf(acc[7] + dv2 * __uint_as_float(ho.w & 0xffff0000u) + bh.w, 0.f);
        uint4 st;
        st.x = (unsigned)f2bf(r0) | ((unsigned)f2bf(r1) << 16);
        st.y = (unsigned)f2bf(r2) | ((unsigned)f2bf(r3) << 16);
        st.z = (unsigned)f2bf(r4) | ((unsigned)f2bf(r5) << 16);
        st.w = (unsigned)f2bf(r6) | ((unsigned)f2bf(r7) << 16);
        *(uint4*)((ushort*)out + (size_t)node * 256 + 192 + q * 8) = st;
    }
}

// layer 2: gather bf16 hrelu (ushort cols [192..255]); write fp32 combined to float[0..63]
__global__ void gather_comb_kernel(const int* __restrict__ rec4, const int* __restrict__ row_start,
                                   const int* __restrict__ cnt, const float* __restrict__ dinv,
                                   float* __restrict__ out, int N) {
    int node = blockIdx.x * 4 + (threadIdx.x >> 6);
    if (node >= N) return;
    int L = threadIdx.x & 63;
    int g = L >> 3;
    int q = L & 7;
    const ushort* hb = (const ushort*)out;
    int beg = row_start[node];
    int n   = cnt[node];
    float dvd = dinv[node];
    float acc[8] = {0.f, 0.f, 0.f, 0.f, 0.f, 0.f, 0.f, 0.f};
    GATHER_CHUNK(192)
    #pragma unroll
    for (int off = 8; off < 64; off <<= 1)
        #pragma unroll
        for (int j = 0; j < 8; ++j)
            acc[j] += __shfl_xor(acc[j], off, 64);
    if (L < 8) {
        float dv2 = dvd * dvd;
        uint4 ho = *(const uint4*)(hb + (size_t)node * 256 + 192 + q * 8);
        float4 o0, o1;
        o0.x = acc[0] + dv2 * __uint_as_float(ho.x << 16);
        o0.y = acc[1] + dv2 * __uint_as_float(ho.x & 0xffff0000u);
        o0.z = acc[2] + dv2 * __uint_as_float(ho.y << 16);
        o0.w = acc[3] + dv2 * __uint_as_float(ho.y & 0xffff0000u);
        o1.x = acc[4] + dv2 * __uint_as_float(ho.z << 16);
        o1.y = acc[5] + dv2 * __uint_as_float(ho.z & 0xffff0000u);
        o1.z = acc[6] + dv2 * __uint_as_float(ho.w << 16);
        o1.w = acc[7] + dv2 * __uint_as_float(ho.w & 0xffff0000u);
        *(float4*)&out[(size_t)node * FO + q * 8]     = o0;
        *(float4*)&out[(size_t)node * FO + q * 8 + 4] = o1;
    }
}

// ---------------- dense kernels ----------------

// mm1 v8 (MFMA, global frags, COLUMN-SPLIT waves): h1 = x @ W1 -> bf16 at ushort[128..191].
// Split-precision: x = xh + xl, W = Wh + Wl; h ~= xh@Wh + xh@Wl + xl@Wh.
// v8 insight (r11): all prior variants were GRID-limited (<=12 waves/CU available).
// Now block = 16 rows, 4 waves; wave w computes cols [16w,16w+16) only ->
// grid 3125 blocks = 12500 waves (~49/CU). The 4 waves read IDENTICAL x rows (L1
// broadcast); each wave streams one 16-col frag slice. No LDS, no barriers.
__global__ __launch_bounds__(256, 4) void mm1_mfma_g(const float* __restrict__ x,
                                                     const short* __restrict__ WH,
                                                     const short* __restrict__ WL,
                                                     float* __restrict__ out, int N) {
    int tid = threadIdx.x;
    int wid = tid >> 6;               // 0..3 = column block
    int l   = tid & 63;
    int R0  = blockIdx.x * 16;
    int rowA = R0 + (l & 15);
    int kg   = l >> 4;
    const float* xr = x + (size_t)rowA * FI;
    bool ok = rowA < N;
    const float4 z4 = make_float4(0.f, 0.f, 0.f, 0.f);

    // issue the wave's x strip: 16 float4/lane (same addrs across the 4 waves -> L1)
    float4 xv[16];
    #pragma unroll
    for (int t = 0; t < 8; ++t) {
        int kb = t * 32 + kg * 8;
        xv[2 * t]     = ok ? *(const float4*)&xr[kb]     : z4;
        xv[2 * t + 1] = ok ? *(const float4*)&xr[kb + 4] : z4;
    }

    f32x4 acc = (f32x4){0.f, 0.f, 0.f, 0.f};

    // frag double-buffer over t (c fixed = wid)
    bf16x8 fh[2], fl[2];
    {
        int e = (wid * 8 + 0) * 64 + l;
        fh[0] = *(const bf16x8*)&WH[(size_t)e * 8];
        fl[0] = *(const bf16x8*)&WL[(size_t)e * 8];
    }

    #pragma unroll
    for (int t = 0; t < 8; ++t) {
        const int cur = t & 1, nxt = cur ^ 1;
        if (t < 7) {
            int e = (wid * 8 + (t + 1)) * 64 + l;
            fh[nxt] = *(const bf16x8*)&WH[(size_t)e * 8];
            fl[nxt] = *(const bf16x8*)&WL[(size_t)e * 8];
        }
        bf16x8 ah, al;
        {
            float4 a0 = xv[2 * t], a1 = xv[2 * t + 1];
            float va[8] = {a0.x, a0.y, a0.z, a0.w, a1.x, a1.y, a1.z, a1.w};
            #pragma unroll
            for (int j = 0; j < 8; ++j) {
                ushort h = f2bf(va[j]);
                ah[j] = (short)h;
                al[j] = (short)f2bf(va[j] - bf2f(h));
            }
        }
        acc = __builtin_amdgcn_mfma_f32_16x16x32_bf16(ah, fh[cur], acc, 0, 0, 0);
        acc = __builtin_amdgcn_mfma_f32_16x16x32_bf16(ah, fl[cur], acc, 0, 0, 0);
        acc = __builtin_amdgcn_mfma_f32_16x16x32_bf16(al, fh[cur], acc, 0, 0, 0);
    }
    {
        int rbase = R0 + (l >> 4) * 4;
        #pragma unroll
        for (int r = 0; r < 4; ++r) {
            int row = rbase + r;
            if (row < N) {
                ushort* ob = (ushort*)out + (size_t)row * 256 + 128;
                ob[wid * 16 + (l & 15)] = f2bf(acc[r]);
            }
        }
    }
}

// fallback mm1 (LDS-staged, r8/r9-validated) — workspace-free path only.
__global__ __launch_bounds__(512) void mm1_mfma(const float* __restrict__ x,
                                                const float* __restrict__ W1,
                                                float* __restrict__ out, int N) {
    __shared__ short bfH[2048 * 8];
    __shared__ short bfL[2048 * 8];
    int tid = threadIdx.x;
    #pragma unroll
    for (int i = 0; i < 8; ++i) {
        int f = i * 512 + tid;
        float4 wv = *(const float4*)&W1[(size_t)f * 4];
        int k  = f >> 4;
        int c4 = f & 15;
        int j  = k & 7;
        int e0 = ((c4 >> 2) * 8 + (k >> 5)) * 64 + ((k >> 3) & 3) * 16 + (c4 & 3) * 4;
        float vv[4] = {wv.x, wv.y, wv.z, wv.w};
        #pragma unroll
        for (int cc = 0; cc < 4; ++cc) {
            ushort h = f2bf(vv[cc]);
            bfH[(e0 + cc) * 8 + j] = (short)h;
            bfL[(e0 + cc) * 8 + j] = (short)f2bf(vv[cc] - bf2f(h));
        }
    }
    __syncthreads();
    int wid = tid >> 6;
    int l   = tid & 63;
    int R0  = blockIdx.x * 128;
    int rowA = R0 + wid * 16 + (l & 15);
    int kg   = l >> 4;
    const float* xr = x + (size_t)rowA * FI;
    bool ok = rowA < N;
    const float4 z4 = make_float4(0.f, 0.f, 0.f, 0.f);
    f32x4 acc[4];
    #pragma unroll
    for (int c = 0; c < 4; ++c) acc[c] = (f32x4){0.f, 0.f, 0.f, 0.f};
    float4 xa = ok ? *(const float4*)&xr[kg * 8]     : z4;
    float4 xb = ok ? *(const float4*)&xr[kg * 8 + 4] : z4;
    #pragma unroll
    for (int t = 0; t < 8; ++t) {
        bf16x8 ah, al;
        {
            float va[8] = {xa.x, xa.y, xa.z, xa.w, xb.x, xb.y, xb.z, xb.w};
            #pragma unroll
            for (int j = 0; j < 8; ++j) {
                ushort h = f2bf(va[j]);
                ah[j] = (short)h;
                al[j] = (short)f2bf(va[j] - bf2f(h));
            }
        }
        if (t < 7) {
            int kb = (t + 1) * 32 + kg * 8;
            xa = ok ? *(const float4*)&xr[kb]     : z4;
            xb = ok ? *(const float4*)&xr[kb + 4] : z4;
        }
        #pragma unroll
        for (int c = 0; c < 4; ++c) {
            int e = (c * 8 + t) * 64 + l;
            bf16x8 bh = *(const bf16x8*)&bfH[e * 8];
            bf16x8 bl = *(const bf16x8*)&bfL[e * 8];
            acc[c] = __builtin_amdgcn_mfma_f32_16x16x32_bf16(ah, bh, acc[c], 0, 0, 0);
            acc[c] = __builtin_amdgcn_mfma_f32_16x16x32_bf16(ah, bl, acc[c], 0, 0, 0);
            acc[c] = __builtin_amdgcn_mfma_f32_16x16x32_bf16(al, bh, acc[c], 0, 0, 0);
        }
    }
    {
        int rbase = R0 + wid * 16 + (l >> 4) * 4;
        #pragma unroll
        for (int r = 0; r < 4; ++r) {
            int row = rbase + r;
            if (row < N) {
                ushort* ob = (ushort*)out + (size_t)row * 256 + 128;
                #pragma unroll
                for (int c = 0; c < 4; ++c)
                    ob[c * 16 + (l & 15)] = f2bf(acc[c][r]);
            }
        }
    }
}

// mm2: out_row = combined(float[0..63]) @ W2 + b2, in place.
__global__ __launch_bounds__(256) void mm2_tiled(const float* __restrict__ W2,
                                                 const float* __restrict__ b2,
                                                 float* __restrict__ out, int N) {
    __shared__ float xs[64][68];
    __shared__ float ws[64][128];
    int tid = threadIdx.x;
    int R0  = blockIdx.x * 64;
    int ty  = tid >> 4;
    int tx  = tid & 15;

    {
        int sr = tid >> 2;
        int l4 = tid & 3;
        int grow = R0 + sr;
        bool ok = grow < N;
        const float* orow = out + (size_t)grow * FO;
        #pragma unroll
        for (int q = 0; q < 4; ++q) {
            int j0 = (l4 + 4 * q) * 4;
            float4 a = ok ? *(const float4*)&orow[j0] : make_float4(0.f, 0.f, 0.f, 0.f);
            xs[j0 + 0][sr] = a.x;
            xs[j0 + 1][sr] = a.y;
            xs[j0 + 2][sr] = a.z;
            xs[j0 + 3][sr] = a.w;
        }
    }
    #pragma unroll
    for (int q = 0; q < 8; ++q) {
        int f = tid + q * 256;
        *(float4*)&ws[f >> 5][(f & 31) * 4] = *(const float4*)&W2[(size_t)f * 4];
    }
    __syncthreads();

    float acc[4][8];
    #pragma unroll
    for (int i = 0; i < 4; ++i)
        #pragma unroll
        for (int j = 0; j < 8; ++j) acc[i][j] = 0.f;

    #pragma unroll 4
    for (int k = 0; k < FH; ++k) {
        float4 a  = *(const float4*)&xs[k][ty * 4];
        float4 bl = *(const float4*)&ws[k][tx * 4];
        float4 bh = *(const float4*)&ws[k][64 + tx * 4];
        float av[4] = {a.x, a.y, a.z, a.w};
        float bv[8] = {bl.x, bl.y, bl.z, bl.w, bh.x, bh.y, bh.z, bh.w};
        #pragma unroll
        for (int i = 0; i < 4; ++i)
            #pragma unroll
            for (int j = 0; j < 8; ++j)
                acc[i][j] = fmaf(av[i], bv[j], acc[i][j]);
    }

    float4 b2l = *(const float4*)&b2[tx * 4];
    float4 b2h = *(const float4*)&b2[64 + tx * 4];
    #pragma unroll
    for (int i = 0; i < 4; ++i) {
        int row = R0 + ty * 4 + i;
        if (row < N) {
            float* o = out + (size_t)row * FO;
            *(float4*)&o[tx * 4] = make_float4(acc[i][0] + b2l.x, acc[i][1] + b2l.y,
                                               acc[i][2] + b2l.z, acc[i][3] + b2l.w);
            *(float4*)&o[64 + tx * 4] = make_float4(acc[i][4] + b2h.x, acc[i][5] + b2h.y,
                                                    acc[i][6] + b2h.z, acc[i][7] + b2h.w);
        }
    }
}

// ---------------- fallback (atomic scatter) pieces — all fp32 ----------------

__global__ void expand_hs1_kernel(float* __restrict__ out, int N) {
    int row = blockIdx.x * 4 + (threadIdx.x >> 6);
    if (row >= N) return;
    int lane = threadIdx.x & 63;
    float v = bf2f(((const ushort*)out)[(size_t)row * 256 + 128 + lane]);
    out[(size_t)row * FO + FH + lane] = v;
}

__global__ void zero_half_kernel(float* __restrict__ out, int half, int N) {
    int i = blockIdx.x * 256 + threadIdx.x;
    if (i >= N * FH) return;
    out[(size_t)(i >> 6) * FO + half + (i & 63)] = 0.f;
}

__global__ void scatter_half_kernel(const int* __restrict__ src, const int* __restrict__ dst,
                                    const float* __restrict__ dinv, float* __restrict__ out,
                                    int rh, int wh, int E) {
    int e = blockIdx.x * 4 + (threadIdx.x >> 6);
    if (e >= E) return;
    int lane = threadIdx.x & 63;
    int s = src[e];
    int d = dst[e];
    float w = dinv[s] * dinv[d];
    atomicAdd(&out[(size_t)d * FO + wh + lane], out[(size_t)s * FO + rh + lane] * w);
}

// lower = relu(lower_agg + dv^2*upper_own + b1)
__global__ void finish1_kernel(float* __restrict__ out, const float* __restrict__ dinv,
                               const float* __restrict__ b1, int N) {
    int i = blockIdx.x * 256 + threadIdx.x;
    if (i >= N * FH) return;
    int row = i >> 6;
    int c   = i & 63;
    size_t base = (size_t)row * FO;
    float dv = dinv[row];
    out[base + c] = fmaxf(out[base + c] + dv * dv * out[base + FH + c] + b1[c], 0.f);
}

// lower = upper_agg + dv^2*lower_own   (combined for mm2)
__global__ void finish2_kernel(float* __restrict__ out, const float* __restrict__ dinv, int N) {
    int i = blockIdx.x * 256 + threadIdx.x;
    if (i >= N * FH) return;
    int row = i >> 6;
    int c   = i & 63;
    size_t base = (size_t)row * FO;
    float dv = dinv[row];
    out[base + c] = out[base + FH + c] + dv * dv * out[base + c];
}

extern "C" void kernel_launch(void* const* d_in, const int* in_sizes, int n_in,
                              void* d_out, int out_size, void* d_ws, size_t ws_size,
                              hipStream_t stream) {
    const float* x  = (const float*)d_in[0];
    const int*   ei = (const int*)d_in[1];
    const float* W1 = (const float*)d_in[2];
    const float* b1 = (const float*)d_in[3];
    const float* W2 = (const float*)d_in[4];
    const float* b2 = (const float*)d_in[5];
    float* out = (float*)d_out;

    int N = in_sizes[0] / FI;     // 50000
    int E = in_sizes[1] / 2;      // 1600000
    const int* src = ei;
    const int* dst = ei + E;

    char* w = (char*)d_ws;
    float* dinv        = (float*)w;      w += (size_t)N * 4;
    int*   cnt         = (int*)w;        w += (size_t)N * 4;
    int*   row_start   = (int*)w;        w += (size_t)N * 4;
    int*   bucket_cnt  = (int*)w;        w += 256 * 4;
    int*   bucket_pos  = (int*)w;        w += 256 * 4;
    int*   bucket_base = (int*)w;        w += 260 * 4;
    short* wfragH      = (short*)w;      w += 2048 * 8 * 2;   // 32KB
    short* wfragL      = (short*)w;      w += 2048 * 8 * 2;   // 32KB
    unsigned* binned   = (unsigned*)w;   w += (size_t)E * 4;
    int*   rec4        = (int*)w;        w += (size_t)E * 4;
    size_t need = (size_t)(w - (char*)d_ws);   // ~13.5 MB

    int nblkA = (E + ASORT_CHUNK - 1) / ASORT_CHUNK;   // 782
    int nbk   = (N + 255) >> 8;                        // 196 buckets for N=50000

    if (ws_size >= need && N <= 65536) {
        zero_i32<<<1, 256, 0, stream>>>(bucket_cnt, 256);
        hist_wprep_kernel<<<nblkA + 16, 256, 0, stream>>>(dst, bucket_cnt, W1, wfragH, wfragL, E, nblkA);
        bucket_scan_kernel<<<1, 256, 0, stream>>>(bucket_cnt, bucket_base, bucket_pos, E);
        binA_kernel<<<nblkA, 256, 0, stream>>>(src, dst, bucket_pos, binned, E);
        binB_kernel<<<nbk, 256, 0, stream>>>(bucket_base, binned, rec4, row_start, cnt, dinv, N);

        mm1_mfma_g<<<(N + 15) / 16, 256, 0, stream>>>(x, wfragH, wfragL, out, N);
        gather_relu_kernel<<<(N + 3) / 4, 256, 0, stream>>>(rec4, row_start, cnt, dinv, b1, out, N);
        gather_comb_kernel<<<(N + 3) / 4, 256, 0, stream>>>(rec4, row_start, cnt, dinv, out, N);
        mm2_tiled<<<(N + 63) / 64, 256, 0, stream>>>(W2, b2, out, N);
    } else {
        // fallback: atomic scatter path, all fp32 (LDS-staged mm1)
        zero_i32<<<(N + 255) / 256, 256, 0, stream>>>(cnt, N);
        deg_cnt_kernel<<<(E + 1023) / 1024, 256, 0, stream>>>(dst, cnt, E);
        dinv_kernel<<<(N + 255) / 256, 256, 0, stream>>>(cnt, dinv, N);
        mm1_mfma<<<(N + 127) / 128, 512, 0, stream>>>(x, W1, out, N);
        expand_hs1_kernel<<<(N + 3) / 4, 256, 0, stream>>>(out, N);
        zero_half_kernel<<<((N * FH) + 255) / 256, 256, 0, stream>>>(out, 0, N);
        scatter_half_kernel<<<(E + 3) / 4, 256, 0, stream>>>(src, dst, dinv, out, FH, 0, E);
        finish1_kernel<<<((N * FH) + 255) / 256, 256, 0, stream>>>(out, dinv, b1, N);
        zero_half_kernel<<<((N * FH) + 255) / 256, 256, 0, stream>>>(out, FH, N);
        scatter_half_kernel<<<(E + 3) / 4, 256, 0, stream>>>(src, dst, dinv, out, 0, FH, E);
        finish2_kernel<<<((N * FH) + 255) / 256, 256, 0, stream>>>(out, dinv, N);
        mm2_tiled<<<(N + 63) / 64, 256, 0, stream>>>(W2, b2, out, N);
    }
}

// Round 13
// 273.369 us; speedup vs baseline: 1.2364x; 1.2364x over previous
//
#include <hip/hip_runtime.h>

#define FI 256
#define FH 64
#define FO 128
#define ASORT_CHUNK 2048
// ushort-view row stride 256: bf16 h1 at ushort[128..191], bf16 hrelu at [192..255],
// fp32 combined at float[0..63].

typedef __attribute__((ext_vector_type(8))) short bf16x8;
typedef __attribute__((ext_vector_type(4))) float f32x4;

__device__ __forceinline__ ushort f2bf(float x) {   // fp32 -> bf16 RNE
    unsigned b = __float_as_uint(x);
    b += 0x7fffu + ((b >> 16) & 1u);
    return (ushort)(b >> 16);
}
__device__ __forceinline__ float bf2f(ushort u) {
    return __uint_as_float(((unsigned)u) << 16);
}

// ---------------- small kernels ----------------

__global__ void zero_i32(int* __restrict__ p, int n) {
    int i = blockIdx.x * 256 + threadIdx.x;
    if (i < n) p[i] = 0;
}

__global__ void deg_cnt_kernel(const int* __restrict__ dst, int* __restrict__ cnt, int E) {
    int base = blockIdx.x * 1024 + threadIdx.x;
    #pragma unroll
    for (int q = 0; q < 4; ++q) {
        int e = base + q * 256;
        if (e < E) atomicAdd(&cnt[dst[e]], 1);
    }
}

__global__ void dinv_kernel(const int* __restrict__ cnt, float* __restrict__ dinv, int N) {
    int i = blockIdx.x * 256 + threadIdx.x;
    if (i < N) dinv[i] = rsqrtf((float)cnt[i] + 1.0f);
}

// ---------------- CSR build: bucketed histogram + binned counting sort ----------------

// hist (blocks < nblkA) + W1 fragment prep (16 trailing blocks; no extra launch).
// Frag layout entry e=(c*8+t)*64+l: col=c*16+(l&15), k=t*32+(l>>4)*8+j (validated r8/r9).
__global__ __launch_bounds__(256) void hist_wprep_kernel(const int* __restrict__ dst,
                                                         int* __restrict__ bucket_cnt,
                                                         const float* __restrict__ W1,
                                                         short* __restrict__ WH,
                                                         short* __restrict__ WL,
                                                         int E, int nblkA) {
    if ((int)blockIdx.x >= nblkA) {
        int f = ((int)blockIdx.x - nblkA) * 256 + threadIdx.x;   // float4 idx in 256x64 W1
        float4 wv = *(const float4*)&W1[(size_t)f * 4];
        int k  = f >> 4;
        int c4 = f & 15;
        int j  = k & 7;
        int e0 = ((c4 >> 2) * 8 + (k >> 5)) * 64 + ((k >> 3) & 3) * 16 + (c4 & 3) * 4;
        float vv[4] = {wv.x, wv.y, wv.z, wv.w};
        #pragma unroll
        for (int cc = 0; cc < 4; ++cc) {
            ushort h = f2bf(vv[cc]);
            WH[(e0 + cc) * 8 + j] = (short)h;
            WL[(e0 + cc) * 8 + j] = (short)f2bf(vv[cc] - bf2f(h));
        }
        return;
    }
    __shared__ int lcnt[256];
    int t = threadIdx.x;
    int base = blockIdx.x * ASORT_CHUNK;
    lcnt[t] = 0;
    __syncthreads();
    #pragma unroll
    for (int j = 0; j < 8; ++j) {
        int e = base + j * 256 + t;
        if (e < E) atomicAdd(&lcnt[((unsigned)dst[e]) >> 8], 1);
    }
    __syncthreads();
    int v = lcnt[t];
    if (v > 0) atomicAdd(&bucket_cnt[t], v);
}

__global__ __launch_bounds__(256) void bucket_scan_kernel(const int* __restrict__ bucket_cnt,
                                                          int* __restrict__ bucket_base,
                                                          int* __restrict__ bucket_pos, int E) {
    __shared__ int sc[256];
    int t = threadIdx.x;
    int sum = bucket_cnt[t];
    sc[t] = sum;
    __syncthreads();
    for (int off = 1; off < 256; off <<= 1) {
        int u = (t >= off) ? sc[t - off] : 0;
        __syncthreads();
        sc[t] += u;
        __syncthreads();
    }
    int excl = sc[t] - sum;
    bucket_base[t] = excl;
    bucket_pos[t]  = excl;
    if (t == 255) bucket_base[256] = sc[255];   // == E
}

// Merged dispatch: blocks [0,nblkA) = Pass A (LDS counting sort by dst>>8);
// blocks [nblkA, nblkA+nmm1) = mm1 v6 (MFMA, global frags, NO LDS).
// mm1 is independent of the CSR chain -> its latency-bound waves overlap binA's
// LDS-sort work in the same dispatch (r12 lesson: mm1's interior is request-bound
// at ~45us no matter the structure; hide it instead).
__global__ __launch_bounds__(256) void binA_mm1_kernel(const int* __restrict__ src,
                                                       const int* __restrict__ dst,
                                                       int* __restrict__ bucket_pos,
                                                       unsigned* __restrict__ binned, int E,
                                                       const float* __restrict__ x,
                                                       const short* __restrict__ WH,
                                                       const short* __restrict__ WL,
                                                       float* __restrict__ out, int N,
                                                       int nblkA) {
    if ((int)blockIdx.x >= nblkA) {
        // ---- mm1 v6 path (r10, 45us proven): block = 64 rows, 4 waves x 16 rows ----
        int bid = (int)blockIdx.x - nblkA;
        int tid = threadIdx.x;
        int wid = tid >> 6;
        int l   = tid & 63;
        int R0  = bid * 64;
        int rowA = R0 + wid * 16 + (l & 15);
        int kg   = l >> 4;
        const float* xr = x + (size_t)rowA * FI;
        bool ok = rowA < N;
        const float4 z4 = make_float4(0.f, 0.f, 0.f, 0.f);

        f32x4 acc[4];
        #pragma unroll
        for (int c = 0; c < 4; ++c) acc[c] = (f32x4){0.f, 0.f, 0.f, 0.f};

        float4 xa = ok ? *(const float4*)&xr[kg * 8]     : z4;
        float4 xb = ok ? *(const float4*)&xr[kg * 8 + 4] : z4;

        #pragma unroll
        for (int t = 0; t < 8; ++t) {
            bf16x8 ah, al;
            {
                float va[8] = {xa.x, xa.y, xa.z, xa.w, xb.x, xb.y, xb.z, xb.w};
                #pragma unroll
                for (int j = 0; j < 8; ++j) {
                    ushort h = f2bf(va[j]);
                    ah[j] = (short)h;
                    al[j] = (short)f2bf(va[j] - bf2f(h));
                }
            }
            if (t < 7) {                  // issue next K-tile x loads; fly during MFMAs
                int kb = (t + 1) * 32 + kg * 8;
                xa = ok ? *(const float4*)&xr[kb]     : z4;
                xb = ok ? *(const float4*)&xr[kb + 4] : z4;
            }
            #pragma unroll
            for (int c = 0; c < 4; ++c) {
                int e = (c * 8 + t) * 64 + l;
                bf16x8 bh = *(const bf16x8*)&WH[(size_t)e * 8];
                bf16x8 bl = *(const bf16x8*)&WL[(size_t)e * 8];
                acc[c] = __builtin_amdgcn_mfma_f32_16x16x32_bf16(ah, bh, acc[c], 0, 0, 0);
                acc[c] = __builtin_amdgcn_mfma_f32_16x16x32_bf16(ah, bl, acc[c], 0, 0, 0);
                acc[c] = __builtin_amdgcn_mfma_f32_16x16x32_bf16(al, bh, acc[c], 0, 0, 0);
            }
        }
        {
            int rbase = R0 + wid * 16 + (l >> 4) * 4;
            #pragma unroll
            for (int r = 0; r < 4; ++r) {
                int row = rbase + r;
                if (row < N) {
                    ushort* ob = (ushort*)out + (size_t)row * 256 + 128;
                    #pragma unroll
                    for (int c = 0; c < 4; ++c)
                        ob[c * 16 + (l & 15)] = f2bf(acc[c][r]);
                }
            }
        }
        return;
    }
    // ---- binA path (unchanged) ----
    __shared__ int lcnt[256];
    __shared__ int lbase[256];
    __shared__ int gbase[256];
    __shared__ int sc[256];
    __shared__ unsigned sorted[ASORT_CHUNK];
    int t = threadIdx.x;
    int base = blockIdx.x * ASORT_CHUNK;
    lcnt[t] = 0;
    __syncthreads();
    unsigned pk[8];
    short bb[8];
    short mi[8];
    #pragma unroll
    for (int j = 0; j < 8; ++j) {
        int e = base + j * 256 + t;
        if (e < E) {
            unsigned s = (unsigned)src[e];
            unsigned d = (unsigned)dst[e];
            pk[j] = s | (d << 16);
            int b = (int)(d >> 8);
            bb[j] = (short)b;
            mi[j] = (short)atomicAdd(&lcnt[b], 1);
        } else {
            bb[j] = -1;
        }
    }
    __syncthreads();
    int v = lcnt[t];
    sc[t] = v;
    __syncthreads();
    #pragma unroll
    for (int off = 1; off < 256; off <<= 1) {
        int u = (t >= off) ? sc[t - off] : 0;
        __syncthreads();
        sc[t] += u;
        __syncthreads();
    }
    lbase[t] = sc[t] - v;                       // exclusive prefix
    if (v > 0) gbase[t] = atomicAdd(&bucket_pos[t], v);
    __syncthreads();
    #pragma unroll
    for (int j = 0; j < 8; ++j)
        if (bb[j] >= 0) sorted[lbase[(int)bb[j]] + (int)mi[j]] = pk[j];
    int tot = sc[255];
    __syncthreads();
    for (int i = t; i < tot; i += 256) {
        unsigned vv = sorted[i];
        int b = (int)(vv >> 24);                // dst>>8 (dst < 65536)
        binned[gbase[b] + (i - lbase[b])] = vv;
    }
}

// Pass B: one block per bucket; per-node histogram+scan in LDS, writes row_start/cnt/dinv,
// then scatters rec4 (src-only) inside the bucket's ~32KB region.
__global__ __launch_bounds__(256) void binB_kernel(const int* __restrict__ bucket_base,
                                                   const unsigned* __restrict__ binned,
                                                   int* __restrict__ rec4,
                                                   int* __restrict__ row_start,
                                                   int* __restrict__ cnt,
                                                   float* __restrict__ dinv, int N) {
    __shared__ int lcnt[256];
    __shared__ int sc[256];
    __shared__ int lstart[256];
    __shared__ int loff[256];
    int t = threadIdx.x;
    int d0 = blockIdx.x << 8;
    int start = bucket_base[blockIdx.x];
    int end   = bucket_base[blockIdx.x + 1];
    lcnt[t] = 0;
    __syncthreads();
    for (int i = start + t; i < end; i += 256)
        atomicAdd(&lcnt[(binned[i] >> 16) & 0xffu], 1);
    __syncthreads();
    int v = lcnt[t];
    sc[t] = v;
    __syncthreads();
    for (int off = 1; off < 256; off <<= 1) {
        int u = (t >= off) ? sc[t - off] : 0;
        __syncthreads();
        sc[t] += u;
        __syncthreads();
    }
    int st = start + sc[t] - v;                  // row start for node d0+t
    lstart[t] = st;
    loff[t] = 0;
    if (d0 + t < N) {
        row_start[d0 + t] = st;
        cnt[d0 + t] = v;
        dinv[d0 + t] = rsqrtf((float)v + 1.0f);
    }
    __syncthreads();
    int i = start + t;
    for (; i + 768 < end; i += 1024) {
        unsigned v0 = binned[i];
        unsigned v1 = binned[i + 256];
        unsigned v2 = binned[i + 512];
        unsigned v3 = binned[i + 768];
        int dA = (int)((v0 >> 16) & 0xffu); int kA = atomicAdd(&loff[dA], 1);
        rec4[lstart[dA] + kA] = (int)(v0 & 0xffffu);
        int dB = (int)((v1 >> 16) & 0xffu); int kB = atomicAdd(&loff[dB], 1);
        rec4[lstart[dB] + kB] = (int)(v1 & 0xffffu);
        int dC = (int)((v2 >> 16) & 0xffu); int kC = atomicAdd(&loff[dC], 1);
        rec4[lstart[dC] + kC] = (int)(v2 & 0xffffu);
        int dD = (int)((v3 >> 16) & 0xffu); int kD = atomicAdd(&loff[dD], 1);
        rec4[lstart[dD] + kD] = (int)(v3 & 0xffffu);
    }
    for (; i < end; i += 256) {
        unsigned v4 = binned[i];
        int d = (int)((v4 >> 16) & 0xffu);
        int k = atomicAdd(&loff[d], 1);
        rec4[lstart[d] + k] = (int)(v4 & 0xffffu);
    }
}

// ---------------- gather-side aggregation, v3 ----------------
// Wave = 1 node. Lane L: g = L>>3 (8 edge slots), q = L&7 (8 bf16 = 16B per lane).
// Per 64-edge chunk: cooperative (src,w) preload + shfl broadcast; loads and FMA in
// two statically-indexed unrolled loops -> up to 8 gathers in flight per wave.

#define ACC8(hv, wt)                                                   \
    acc[0] = fmaf(__uint_as_float((hv).x << 16),         wt, acc[0]);  \
    acc[1] = fmaf(__uint_as_float((hv).x & 0xffff0000u), wt, acc[1]);  \
    acc[2] = fmaf(__uint_as_float((hv).y << 16),         wt, acc[2]);  \
    acc[3] = fmaf(__uint_as_float((hv).y & 0xffff0000u), wt, acc[3]);  \
    acc[4] = fmaf(__uint_as_float((hv).z << 16),         wt, acc[4]);  \
    acc[5] = fmaf(__uint_as_float((hv).z & 0xffff0000u), wt, acc[5]);  \
    acc[6] = fmaf(__uint_as_float((hv).w << 16),         wt, acc[6]);  \
    acc[7] = fmaf(__uint_as_float((hv).w & 0xffff0000u), wt, acc[7]);

#define GATHER_CHUNK(OFFS)                                                     \
    for (int c0 = 0; c0 < n; c0 += 64) {                                       \
        int idx_l = c0 + L;                                                    \
        int sreg = node;                                                       \
        float wreg = 0.f;                                                      \
        if (idx_l < n) {                                                       \
            sreg = rec4[beg + idx_l];                                          \
            wreg = dinv[sreg] * dvd;                                           \
        }                                                                      \
        int m = n - c0; if (m > 64) m = 64;                                    \
        int umax = (m + 7) >> 3;                                               \
        uint4 hv[8];                                                           \
        _Pragma("unroll")                                                      \
        for (int u = 0; u < 8; ++u) {                                          \
            if (u < umax) {                                                    \
                int sidx = __shfl(sreg, u * 8 + g, 64);                        \
                hv[u] = *(const uint4*)(hb + (size_t)sidx * 256 + (OFFS) + q * 8); \
            }                                                                  \
        }                                                                      \
        _Pragma("unroll")                                                      \
        for (int u = 0; u < 8; ++u) {                                          \
            if (u < umax) {                                                    \
                float wt = __shfl(wreg, u * 8 + g, 64);                        \
                ACC8(hv[u], wt)                                                \
            }                                                                  \
        }                                                                      \
    }

// layer 1: gather bf16 h1 (ushort cols [128..191]); write bf16 hrelu = relu(acc + dv^2*own + b1)
__global__ void gather_relu_kernel(const int* __restrict__ rec4, const int* __restrict__ row_start,
                                   const int* __restrict__ cnt, const float* __restrict__ dinv,
                                   const float* __restrict__ b1, float* __restrict__ out, int N) {
    int node = blockIdx.x * 4 + (threadIdx.x >> 6);
    if (node >= N) return;
    int L = threadIdx.x & 63;
    int g = L >> 3;
    int q = L & 7;
    const ushort* hb = (const ushort*)out;
    int beg = row_start[node];
    int n   = cnt[node];
    float dvd = dinv[node];
    float acc[8] = {0.f, 0.f, 0.f, 0.f, 0.f, 0.f, 0.f, 0.f};
    GATHER_CHUNK(128)
    #pragma unroll
    for (int off = 8; off < 64; off <<= 1)
        #pragma unroll
        for (int j = 0; j < 8; ++j)
            acc[j] += __shfl_xor(acc[j], off, 64);
    if (L < 8) {
        float dv2 = dvd * dvd;
        uint4 ho = *(const uint4*)(hb + (size_t)node * 256 + 128 + q * 8);
        float4 bl = *(const float4*)&b1[q * 8];
        float4 bh = *(const float4*)&b1[q * 8 + 4];
        float r0 = fmaxf(acc[0] + dv2 * __uint_as_float(ho.x << 16)         + bl.x, 0.f);
        float r1 = fmaxf(acc[1] + dv2 * __uint_as_float(ho.x & 0xffff0000u) + bl.y, 0.f);
        float r2 = fmaxf(acc[2] + dv2 * __uint_as_float(ho.y << 16)         + bl.z, 0.f);
        float r3 = fmaxf(acc[3] + dv2 * __uint_as_float(ho.y & 0xffff0000u) + bl.w, 0.f);
        float r4 = fmaxf(acc[4] + dv2 * __uint_as_float(ho.z << 16)         + bh.x, 0.f);
        float r5 = fmaxf(acc[5] + dv2 * __uint_as_float(ho.z & 0xffff0000u) + bh.y, 0.f);
        float r6 = fmaxf(acc[6] + dv2 * __uint_as_float(ho.w << 16)         + bh.z, 0.f);
        float r7 = fmaxf(acc[7] + dv2 * __uint_as_float(ho.w & 0xffff0000u) + bh.w, 0.f);
        uint4 st;
        st.x = (unsigned)f2bf(r0) | ((unsigned)f2bf(r1) << 16);
        st.y = (unsigned)f2bf(r2) | ((unsigned)f2bf(r3) << 16);
        st.z = (unsigned)f2bf(r4) | ((unsigned)f2bf(r5) << 16);
        st.w = (unsigned)f2bf(r6) | ((unsigned)f2bf(r7) << 16);
        *(uint4*)((ushort*)out + (size_t)node * 256 + 192 + q * 8) = st;
    }
}

// layer 2: gather bf16 hrelu (ushort cols [192..255]); write fp32 combined to float[0..63]
__global__ void gather_comb_kernel(const int* __restrict__ rec4, const int* __restrict__ row_start,
                                   const int* __restrict__ cnt, const float* __restrict__ dinv,
                                   float* __restrict__ out, int N) {
    int node = blockIdx.x * 4 + (threadIdx.x >> 6);
    if (node >= N) return;
    int L = threadIdx.x & 63;
    int g = L >> 3;
    int q = L & 7;
    const ushort* hb = (const ushort*)out;
    int beg = row_start[node];
    int n   = cnt[node];
    float dvd = dinv[node];
    float acc[8] = {0.f, 0.f, 0.f, 0.f, 0.f, 0.f, 0.f, 0.f};
    GATHER_CHUNK(192)
    #pragma unroll
    for (int off = 8; off < 64; off <<= 1)
        #pragma unroll
        for (int j = 0; j < 8; ++j)
            acc[j] += __shfl_xor(acc[j], off, 64);
    if (L < 8) {
        float dv2 = dvd * dvd;
        uint4 ho = *(const uint4*)(hb + (size_t)node * 256 + 192 + q * 8);
        float4 o0, o1;
        o0.x = acc[0] + dv2 * __uint_as_float(ho.x << 16);
        o0.y = acc[1] + dv2 * __uint_as_float(ho.x & 0xffff0000u);
        o0.z = acc[2] + dv2 * __uint_as_float(ho.y << 16);
        o0.w = acc[3] + dv2 * __uint_as_float(ho.y & 0xffff0000u);
        o1.x = acc[4] + dv2 * __uint_as_float(ho.z << 16);
        o1.y = acc[5] + dv2 * __uint_as_float(ho.z & 0xffff0000u);
        o1.z = acc[6] + dv2 * __uint_as_float(ho.w << 16);
        o1.w = acc[7] + dv2 * __uint_as_float(ho.w & 0xffff0000u);
        *(float4*)&out[(size_t)node * FO + q * 8]     = o0;
        *(float4*)&out[(size_t)node * FO + q * 8 + 4] = o1;
    }
}

// ---------------- dense kernels ----------------

// fallback mm1 (LDS-staged, r8/r9-validated) — workspace-free path only.
__global__ __launch_bounds__(512) void mm1_mfma(const float* __restrict__ x,
                                                const float* __restrict__ W1,
                                                float* __restrict__ out, int N) {
    __shared__ short bfH[2048 * 8];
    __shared__ short bfL[2048 * 8];
    int tid = threadIdx.x;
    #pragma unroll
    for (int i = 0; i < 8; ++i) {
        int f = i * 512 + tid;
        float4 wv = *(const float4*)&W1[(size_t)f * 4];
        int k  = f >> 4;
        int c4 = f & 15;
        int j  = k & 7;
        int e0 = ((c4 >> 2) * 8 + (k >> 5)) * 64 + ((k >> 3) & 3) * 16 + (c4 & 3) * 4;
        float vv[4] = {wv.x, wv.y, wv.z, wv.w};
        #pragma unroll
        for (int cc = 0; cc < 4; ++cc) {
            ushort h = f2bf(vv[cc]);
            bfH[(e0 + cc) * 8 + j] = (short)h;
            bfL[(e0 + cc) * 8 + j] = (short)f2bf(vv[cc] - bf2f(h));
        }
    }
    __syncthreads();
    int wid = tid >> 6;
    int l   = tid & 63;
    int R0  = blockIdx.x * 128;
    int rowA = R0 + wid * 16 + (l & 15);
    int kg   = l >> 4;
    const float* xr = x + (size_t)rowA * FI;
    bool ok = rowA < N;
    const float4 z4 = make_float4(0.f, 0.f, 0.f, 0.f);
    f32x4 acc[4];
    #pragma unroll
    for (int c = 0; c < 4; ++c) acc[c] = (f32x4){0.f, 0.f, 0.f, 0.f};
    float4 xa = ok ? *(const float4*)&xr[kg * 8]     : z4;
    float4 xb = ok ? *(const float4*)&xr[kg * 8 + 4] : z4;
    #pragma unroll
    for (int t = 0; t < 8; ++t) {
        bf16x8 ah, al;
        {
            float va[8] = {xa.x, xa.y, xa.z, xa.w, xb.x, xb.y, xb.z, xb.w};
            #pragma unroll
            for (int j = 0; j < 8; ++j) {
                ushort h = f2bf(va[j]);
                ah[j] = (short)h;
                al[j] = (short)f2bf(va[j] - bf2f(h));
            }
        }
        if (t < 7) {
            int kb = (t + 1) * 32 + kg * 8;
            xa = ok ? *(const float4*)&xr[kb]     : z4;
            xb = ok ? *(const float4*)&xr[kb + 4] : z4;
        }
        #pragma unroll
        for (int c = 0; c < 4; ++c) {
            int e = (c * 8 + t) * 64 + l;
            bf16x8 bh = *(const bf16x8*)&bfH[e * 8];
            bf16x8 bl = *(const bf16x8*)&bfL[e * 8];
            acc[c] = __builtin_amdgcn_mfma_f32_16x16x32_bf16(ah, bh, acc[c], 0, 0, 0);
            acc[c] = __builtin_amdgcn_mfma_f32_16x16x32_bf16(ah, bl, acc[c], 0, 0, 0);
            acc[c] = __builtin_amdgcn_mfma_f32_16x16x32_bf16(al, bh, acc[c], 0, 0, 0);
        }
    }
    {
        int rbase = R0 + wid * 16 + (l >> 4) * 4;
        #pragma unroll
        for (int r = 0; r < 4; ++r) {
            int row = rbase + r;
            if (row < N) {
                ushort* ob = (ushort*)out + (size_t)row * 256 + 128;
                #pragma unroll
                for (int c = 0; c < 4; ++c)
                    ob[c * 16 + (l & 15)] = f2bf(acc[c][r]);
            }
        }
    }
}

// mm2: out_row = combined(float[0..63]) @ W2 + b2, in place.
__global__ __launch_bounds__(256) void mm2_tiled(const float* __restrict__ W2,
                                                 const float* __restrict__ b2,
                                                 float* __restrict__ out, int N) {
    __shared__ float xs[64][68];
    __shared__ float ws[64][128];
    int tid = threadIdx.x;
    int R0  = blockIdx.x * 64;
    int ty  = tid >> 4;
    int tx  = tid & 15;

    {
        int sr = tid >> 2;
        int l4 = tid & 3;
        int grow = R0 + sr;
        bool ok = grow < N;
        const float* orow = out + (size_t)grow * FO;
        #pragma unroll
        for (int q = 0; q < 4; ++q) {
            int j0 = (l4 + 4 * q) * 4;
            float4 a = ok ? *(const float4*)&orow[j0] : make_float4(0.f, 0.f, 0.f, 0.f);
            xs[j0 + 0][sr] = a.x;
            xs[j0 + 1][sr] = a.y;
            xs[j0 + 2][sr] = a.z;
            xs[j0 + 3][sr] = a.w;
        }
    }
    #pragma unroll
    for (int q = 0; q < 8; ++q) {
        int f = tid + q * 256;
        *(float4*)&ws[f >> 5][(f & 31) * 4] = *(const float4*)&W2[(size_t)f * 4];
    }
    __syncthreads();

    float acc[4][8];
    #pragma unroll
    for (int i = 0; i < 4; ++i)
        #pragma unroll
        for (int j = 0; j < 8; ++j) acc[i][j] = 0.f;

    #pragma unroll 4
    for (int k = 0; k < FH; ++k) {
        float4 a  = *(const float4*)&xs[k][ty * 4];
        float4 bl = *(const float4*)&ws[k][tx * 4];
        float4 bh = *(const float4*)&ws[k][64 + tx * 4];
        float av[4] = {a.x, a.y, a.z, a.w};
        float bv[8] = {bl.x, bl.y, bl.z, bl.w, bh.x, bh.y, bh.z, bh.w};
        #pragma unroll
        for (int i = 0; i < 4; ++i)
            #pragma unroll
            for (int j = 0; j < 8; ++j)
                acc[i][j] = fmaf(av[i], bv[j], acc[i][j]);
    }

    float4 b2l = *(const float4*)&b2[tx * 4];
    float4 b2h = *(const float4*)&b2[64 + tx * 4];
    #pragma unroll
    for (int i = 0; i < 4; ++i) {
        int row = R0 + ty * 4 + i;
        if (row < N) {
            float* o = out + (size_t)row * FO;
            *(float4*)&o[tx * 4] = make_float4(acc[i][0] + b2l.x, acc[i][1] + b2l.y,
                                               acc[i][2] + b2l.z, acc[i][3] + b2l.w);
            *(float4*)&o[64 + tx * 4] = make_float4(acc[i][4] + b2h.x, acc[i][5] + b2h.y,
                                                    acc[i][6] + b2h.z, acc[i][7] + b2h.w);
        }
    }
}

// ---------------- fallback (atomic scatter) pieces — all fp32 ----------------

__global__ void expand_hs1_kernel(float* __restrict__ out, int N) {
    int row = blockIdx.x * 4 + (threadIdx.x >> 6);
    if (row >= N) return;
    int lane = threadIdx.x & 63;
    float v = bf2f(((const ushort*)out)[(size_t)row * 256 + 128 + lane]);
    out[(size_t)row * FO + FH + lane] = v;
}

__global__ void zero_half_kernel(float* __restrict__ out, int half, int N) {
    int i = blockIdx.x * 256 + threadIdx.x;
    if (i >= N * FH) return;
    out[(size_t)(i >> 6) * FO + half + (i & 63)] = 0.f;
}

__global__ void scatter_half_kernel(const int* __restrict__ src, const int* __restrict__ dst,
                                    const float* __restrict__ dinv, float* __restrict__ out,
                                    int rh, int wh, int E) {
    int e = blockIdx.x * 4 + (threadIdx.x >> 6);
    if (e >= E) return;
    int lane = threadIdx.x & 63;
    int s = src[e];
    int d = dst[e];
    float w = dinv[s] * dinv[d];
    atomicAdd(&out[(size_t)d * FO + wh + lane], out[(size_t)s * FO + rh + lane] * w);
}

// lower = relu(lower_agg + dv^2*upper_own + b1)
__global__ void finish1_kernel(float* __restrict__ out, const float* __restrict__ dinv,
                               const float* __restrict__ b1, int N) {
    int i = blockIdx.x * 256 + threadIdx.x;
    if (i >= N * FH) return;
    int row = i >> 6;
    int c   = i & 63;
    size_t base = (size_t)row * FO;
    float dv = dinv[row];
    out[base + c] = fmaxf(out[base + c] + dv * dv * out[base + FH + c] + b1[c], 0.f);
}

// lower = upper_agg + dv^2*lower_own   (combined for mm2)
__global__ void finish2_kernel(float* __restrict__ out, const float* __restrict__ dinv, int N) {
    int i = blockIdx.x * 256 + threadIdx.x;
    if (i >= N * FH) return;
    int row = i >> 6;
    int c   = i & 63;
    size_t base = (size_t)row * FO;
    float dv = dinv[row];
    out[base + c] = out[base + FH + c] + dv * dv * out[base + c];
}

extern "C" void kernel_launch(void* const* d_in, const int* in_sizes, int n_in,
                              void* d_out, int out_size, void* d_ws, size_t ws_size,
                              hipStream_t stream) {
    const float* x  = (const float*)d_in[0];
    const int*   ei = (const int*)d_in[1];
    const float* W1 = (const float*)d_in[2];
    const float* b1 = (const float*)d_in[3];
    const float* W2 = (const float*)d_in[4];
    const float* b2 = (const float*)d_in[5];
    float* out = (float*)d_out;

    int N = in_sizes[0] / FI;     // 50000
    int E = in_sizes[1] / 2;      // 1600000
    const int* src = ei;
    const int* dst = ei + E;

    char* w = (char*)d_ws;
    float* dinv        = (float*)w;      w += (size_t)N * 4;
    int*   cnt         = (int*)w;        w += (size_t)N * 4;
    int*   row_start   = (int*)w;        w += (size_t)N * 4;
    int*   bucket_cnt  = (int*)w;        w += 256 * 4;
    int*   bucket_pos  = (int*)w;        w += 256 * 4;
    int*   bucket_base = (int*)w;        w += 260 * 4;
    short* wfragH      = (short*)w;      w += 2048 * 8 * 2;   // 32KB
    short* wfragL      = (short*)w;      w += 2048 * 8 * 2;   // 32KB
    unsigned* binned   = (unsigned*)w;   w += (size_t)E * 4;
    int*   rec4        = (int*)w;        w += (size_t)E * 4;
    size_t need = (size_t)(w - (char*)d_ws);   // ~13.5 MB

    int nblkA = (E + ASORT_CHUNK - 1) / ASORT_CHUNK;   // 782
    int nmm1  = (N + 63) / 64;                         // 782
    int nbk   = (N + 255) >> 8;                        // 196 buckets for N=50000

    if (ws_size >= need && N <= 65536) {
        zero_i32<<<1, 256, 0, stream>>>(bucket_cnt, 256);
        hist_wprep_kernel<<<nblkA + 16, 256, 0, stream>>>(dst, bucket_cnt, W1, wfragH, wfragL, E, nblkA);
        bucket_scan_kernel<<<1, 256, 0, stream>>>(bucket_cnt, bucket_base, bucket_pos, E);
        binA_mm1_kernel<<<nblkA + nmm1, 256, 0, stream>>>(src, dst, bucket_pos, binned, E,
                                                          x, wfragH, wfragL, out, N, nblkA);
        binB_kernel<<<nbk, 256, 0, stream>>>(bucket_base, binned, rec4, row_start, cnt, dinv, N);

        gather_relu_kernel<<<(N + 3) / 4, 256, 0, stream>>>(rec4, row_start, cnt, dinv, b1, out, N);
        gather_comb_kernel<<<(N + 3) / 4, 256, 0, stream>>>(rec4, row_start, cnt, dinv, out, N);
        mm2_tiled<<<(N + 63) / 64, 256, 0, stream>>>(W2, b2, out, N);
    } else {
        // fallback: atomic scatter path, all fp32 (LDS-staged mm1)
        zero_i32<<<(N + 255) / 256, 256, 0, stream>>>(cnt, N);
        deg_cnt_kernel<<<(E + 1023) / 1024, 256, 0, stream>>>(dst, cnt, E);
        dinv_kernel<<<(N + 255) / 256, 256, 0, stream>>>(cnt, dinv, N);
        mm1_mfma<<<(N + 127) / 128, 512, 0, stream>>>(x, W1, out, N);
        expand_hs1_kernel<<<(N + 3) / 4, 256, 0, stream>>>(out, N);
        zero_half_kernel<<<((N * FH) + 255) / 256, 256, 0, stream>>>(out, 0, N);
        scatter_half_kernel<<<(E + 3) / 4, 256, 0, stream>>>(src, dst, dinv, out, FH, 0, E);
        finish1_kernel<<<((N * FH) + 255) / 256, 256, 0, stream>>>(out, dinv, b1, N);
        zero_half_kernel<<<((N * FH) + 255) / 256, 256, 0, stream>>>(out, FH, N);
        scatter_half_kernel<<<(E + 3) / 4, 256, 0, stream>>>(src, dst, dinv, out, 0, FH, E);
        finish2_kernel<<<((N * FH) + 255) / 256, 256, 0, stream>>>(out, dinv, N);
        mm2_tiled<<<(N + 63) / 64, 256, 0, stream>>>(W2, b2, out, N);
    }
}

// Round 14
// 265.109 us; speedup vs baseline: 1.2749x; 1.0312x over previous
//
#include <hip/hip_runtime.h>

#define FI 256
#define FH 64
#define FO 128
#define ASORT_CHUNK 2048
// ushort-view row stride 256: bf16 h1 at ushort[128..191], bf16 hrelu at [192..255],
// fp32 combined at float[0..63].

typedef __attribute__((ext_vector_type(8))) short bf16x8;
typedef __attribute__((ext_vector_type(4))) float f32x4;

__device__ __forceinline__ ushort f2bf(float x) {   // fp32 -> bf16 RNE
    unsigned b = __float_as_uint(x);
    b += 0x7fffu + ((b >> 16) & 1u);
    return (ushort)(b >> 16);
}
__device__ __forceinline__ float bf2f(ushort u) {
    return __uint_as_float(((unsigned)u) << 16);
}

// ---------------- small kernels ----------------

__global__ void zero_i32(int* __restrict__ p, int n) {
    int i = blockIdx.x * 256 + threadIdx.x;
    if (i < n) p[i] = 0;
}

__global__ void deg_cnt_kernel(const int* __restrict__ dst, int* __restrict__ cnt, int E) {
    int base = blockIdx.x * 1024 + threadIdx.x;
    #pragma unroll
    for (int q = 0; q < 4; ++q) {
        int e = base + q * 256;
        if (e < E) atomicAdd(&cnt[dst[e]], 1);
    }
}

__global__ void dinv_kernel(const int* __restrict__ cnt, float* __restrict__ dinv, int N) {
    int i = blockIdx.x * 256 + threadIdx.x;
    if (i < N) dinv[i] = rsqrtf((float)cnt[i] + 1.0f);
}

// ---------------- CSR build: bucketed histogram + binned counting sort ----------------

// hist (blocks < nblkA) + W1 fragment prep (16 trailing blocks; no extra launch).
// Frag layout entry e=(c*8+t)*64+l: col=c*16+(l&15), k=t*32+(l>>4)*8+j (validated r8/r9).
__global__ __launch_bounds__(256) void hist_wprep_kernel(const int* __restrict__ dst,
                                                         int* __restrict__ bucket_cnt,
                                                         const float* __restrict__ W1,
                                                         short* __restrict__ WH,
                                                         short* __restrict__ WL,
                                                         int E, int nblkA) {
    if ((int)blockIdx.x >= nblkA) {
        int f = ((int)blockIdx.x - nblkA) * 256 + threadIdx.x;   // float4 idx in 256x64 W1
        float4 wv = *(const float4*)&W1[(size_t)f * 4];
        int k  = f >> 4;
        int c4 = f & 15;
        int j  = k & 7;
        int e0 = ((c4 >> 2) * 8 + (k >> 5)) * 64 + ((k >> 3) & 3) * 16 + (c4 & 3) * 4;
        float vv[4] = {wv.x, wv.y, wv.z, wv.w};
        #pragma unroll
        for (int cc = 0; cc < 4; ++cc) {
            ushort h = f2bf(vv[cc]);
            WH[(e0 + cc) * 8 + j] = (short)h;
            WL[(e0 + cc) * 8 + j] = (short)f2bf(vv[cc] - bf2f(h));
        }
        return;
    }
    __shared__ int lcnt[256];
    int t = threadIdx.x;
    int base = blockIdx.x * ASORT_CHUNK;
    lcnt[t] = 0;
    __syncthreads();
    #pragma unroll
    for (int j = 0; j < 8; ++j) {
        int e = base + j * 256 + t;
        if (e < E) atomicAdd(&lcnt[((unsigned)dst[e]) >> 8], 1);
    }
    __syncthreads();
    int v = lcnt[t];
    if (v > 0) atomicAdd(&bucket_cnt[t], v);
}

__global__ __launch_bounds__(256) void bucket_scan_kernel(const int* __restrict__ bucket_cnt,
                                                          int* __restrict__ bucket_base,
                                                          int* __restrict__ bucket_pos, int E) {
    __shared__ int sc[256];
    int t = threadIdx.x;
    int sum = bucket_cnt[t];
    sc[t] = sum;
    __syncthreads();
    for (int off = 1; off < 256; off <<= 1) {
        int u = (t >= off) ? sc[t - off] : 0;
        __syncthreads();
        sc[t] += u;
        __syncthreads();
    }
    int excl = sc[t] - sum;
    bucket_base[t] = excl;
    bucket_pos[t]  = excl;
    if (t == 255) bucket_base[256] = sc[255];   // == E
}

// Merged dispatch: blocks [0,nblkA) = Pass A (LDS counting sort by dst>>8);
// blocks [nblkA, nblkA+nmm1) = mm1 v9 (MFMA; x coalesced through wave-private LDS).
// r13 lesson: mm1's wall was REQUEST RATE — scattered 32B A-operand loads. v9 loads
// x coalesced (128B segments), converts to bf16 h/l, bounces through 8KB/wave LDS
// (XOR-swizzled, 2-way reads, no barriers), K processed in two 128-halves.
// smem is a 32KB union: binA layout (12KB) or mm1 layout (4 waves x 8KB).
__global__ __launch_bounds__(256) void binA_mm1_kernel(const int* __restrict__ src,
                                                       const int* __restrict__ dst,
                                                       int* __restrict__ bucket_pos,
                                                       unsigned* __restrict__ binned, int E,
                                                       const float* __restrict__ x,
                                                       const short* __restrict__ WH,
                                                       const short* __restrict__ WL,
                                                       float* __restrict__ out, int N,
                                                       int nblkA) {
    __shared__ __align__(16) char smem[32768];
    if ((int)blockIdx.x >= nblkA) {
        // ---- mm1 v9 path: block = 64 rows, 4 waves x 16 rows, wave-private LDS ----
        int bid = (int)blockIdx.x - nblkA;
        int tid = threadIdx.x;
        int wid = tid >> 6;
        int l   = tid & 63;
        int R0  = bid * 64 + wid * 16;          // wave's 16-row strip
        char* LH = smem + wid * 8192;           // [16][128] bf16 hi, row stride 256B, swizzled
        char* LL = LH + 4096;                   // lo plane
        const float4 z4 = make_float4(0.f, 0.f, 0.f, 0.f);

        f32x4 acc[4];
        #pragma unroll
        for (int c = 0; c < 4; ++c) acc[c] = (f32x4){0.f, 0.f, 0.f, 0.f};

        #pragma unroll
        for (int half = 0; half < 2; ++half) {
            // stage: 16 rows x 128 k, coalesced float4 loads -> cvt -> swizzled LDS
            #pragma unroll
            for (int it = 0; it < 8; ++it) {
                int f   = it * 64 + l;          // 0..511
                int row = f >> 5;               // 0..15
                int c4  = f & 31;               // float4 within the 128-k half
                int grow = R0 + row;
                float4 v = (grow < N) ? *(const float4*)&x[(size_t)grow * FI + half * 128 + c4 * 4]
                                      : z4;
                ushort h0 = f2bf(v.x), h1 = f2bf(v.y), h2 = f2bf(v.z), h3 = f2bf(v.w);
                uint2 hw, lw;
                hw.x = (unsigned)h0 | ((unsigned)h1 << 16);
                hw.y = (unsigned)h2 | ((unsigned)h3 << 16);
                lw.x = (unsigned)f2bf(v.x - bf2f(h0)) | ((unsigned)f2bf(v.y - bf2f(h1)) << 16);
                lw.y = (unsigned)f2bf(v.z - bf2f(h2)) | ((unsigned)f2bf(v.w - bf2f(h3)) << 16);
                int byt = (row * 256 + c4 * 8) ^ ((row & 7) << 4);
                *(uint2*)(LH + byt) = hw;
                *(uint2*)(LL + byt) = lw;
            }
            // compute the 4 K-tiles of this half
            #pragma unroll
            for (int tl = 0; tl < 4; ++tl) {
                int t = half * 4 + tl;
                int r = l & 15, kg = l >> 4;
                int byt = (r * 256 + tl * 64 + kg * 16) ^ ((r & 7) << 4);
                bf16x8 ah = *(const bf16x8*)(LH + byt);
                bf16x8 al = *(const bf16x8*)(LL + byt);
                #pragma unroll
                for (int c = 0; c < 4; ++c) {
                    int e = (c * 8 + t) * 64 + l;
                    bf16x8 bh = *(const bf16x8*)&WH[(size_t)e * 8];
                    bf16x8 bl = *(const bf16x8*)&WL[(size_t)e * 8];
                    acc[c] = __builtin_amdgcn_mfma_f32_16x16x32_bf16(ah, bh, acc[c], 0, 0, 0);
                    acc[c] = __builtin_amdgcn_mfma_f32_16x16x32_bf16(ah, bl, acc[c], 0, 0, 0);
                    acc[c] = __builtin_amdgcn_mfma_f32_16x16x32_bf16(al, bh, acc[c], 0, 0, 0);
                }
            }
        }
        {
            int rbase = R0 + (l >> 4) * 4;
            #pragma unroll
            for (int r = 0; r < 4; ++r) {
                int row = rbase + r;
                if (row < N) {
                    ushort* ob = (ushort*)out + (size_t)row * 256 + 128;
                    #pragma unroll
                    for (int c = 0; c < 4; ++c)
                        ob[c * 16 + (l & 15)] = f2bf(acc[c][r]);
                }
            }
        }
        return;
    }
    // ---- binA path (unchanged; smem union layout) ----
    int* lcnt   = (int*)smem;                   // 256
    int* lbase  = (int*)smem + 256;
    int* gbase  = (int*)smem + 512;
    int* sc     = (int*)smem + 768;
    unsigned* sorted = (unsigned*)(smem + 4096);   // 2048 entries
    int t = threadIdx.x;
    int base = blockIdx.x * ASORT_CHUNK;
    lcnt[t] = 0;
    __syncthreads();
    unsigned pk[8];
    short bb[8];
    short mi[8];
    #pragma unroll
    for (int j = 0; j < 8; ++j) {
        int e = base + j * 256 + t;
        if (e < E) {
            unsigned s = (unsigned)src[e];
            unsigned d = (unsigned)dst[e];
            pk[j] = s | (d << 16);
            int b = (int)(d >> 8);
            bb[j] = (short)b;
            mi[j] = (short)atomicAdd(&lcnt[b], 1);
        } else {
            bb[j] = -1;
        }
    }
    __syncthreads();
    int v = lcnt[t];
    sc[t] = v;
    __syncthreads();
    #pragma unroll
    for (int off = 1; off < 256; off <<= 1) {
        int u = (t >= off) ? sc[t - off] : 0;
        __syncthreads();
        sc[t] += u;
        __syncthreads();
    }
    lbase[t] = sc[t] - v;                       // exclusive prefix
    if (v > 0) gbase[t] = atomicAdd(&bucket_pos[t], v);
    __syncthreads();
    #pragma unroll
    for (int j = 0; j < 8; ++j)
        if (bb[j] >= 0) sorted[lbase[(int)bb[j]] + (int)mi[j]] = pk[j];
    int tot = sc[255];
    __syncthreads();
    for (int i = t; i < tot; i += 256) {
        unsigned vv = sorted[i];
        int b = (int)(vv >> 24);                // dst>>8 (dst < 65536)
        binned[gbase[b] + (i - lbase[b])] = vv;
    }
}

// Pass B: one block per bucket; per-node histogram+scan in LDS, writes row_start/cnt/dinv,
// then scatters rec4 (src-only) inside the bucket's ~32KB region.
__global__ __launch_bounds__(256) void binB_kernel(const int* __restrict__ bucket_base,
                                                   const unsigned* __restrict__ binned,
                                                   int* __restrict__ rec4,
                                                   int* __restrict__ row_start,
                                                   int* __restrict__ cnt,
                                                   float* __restrict__ dinv, int N) {
    __shared__ int lcnt[256];
    __shared__ int sc[256];
    __shared__ int lstart[256];
    __shared__ int loff[256];
    int t = threadIdx.x;
    int d0 = blockIdx.x << 8;
    int start = bucket_base[blockIdx.x];
    int end   = bucket_base[blockIdx.x + 1];
    lcnt[t] = 0;
    __syncthreads();
    for (int i = start + t; i < end; i += 256)
        atomicAdd(&lcnt[(binned[i] >> 16) & 0xffu], 1);
    __syncthreads();
    int v = lcnt[t];
    sc[t] = v;
    __syncthreads();
    for (int off = 1; off < 256; off <<= 1) {
        int u = (t >= off) ? sc[t - off] : 0;
        __syncthreads();
        sc[t] += u;
        __syncthreads();
    }
    int st = start + sc[t] - v;                  // row start for node d0+t
    lstart[t] = st;
    loff[t] = 0;
    if (d0 + t < N) {
        row_start[d0 + t] = st;
        cnt[d0 + t] = v;
        dinv[d0 + t] = rsqrtf((float)v + 1.0f);
    }
    __syncthreads();
    int i = start + t;
    for (; i + 768 < end; i += 1024) {
        unsigned v0 = binned[i];
        unsigned v1 = binned[i + 256];
        unsigned v2 = binned[i + 512];
        unsigned v3 = binned[i + 768];
        int dA = (int)((v0 >> 16) & 0xffu); int kA = atomicAdd(&loff[dA], 1);
        rec4[lstart[dA] + kA] = (int)(v0 & 0xffffu);
        int dB = (int)((v1 >> 16) & 0xffu); int kB = atomicAdd(&loff[dB], 1);
        rec4[lstart[dB] + kB] = (int)(v1 & 0xffffu);
        int dC = (int)((v2 >> 16) & 0xffu); int kC = atomicAdd(&loff[dC], 1);
        rec4[lstart[dC] + kC] = (int)(v2 & 0xffffu);
        int dD = (int)((v3 >> 16) & 0xffu); int kD = atomicAdd(&loff[dD], 1);
        rec4[lstart[dD] + kD] = (int)(v3 & 0xffffu);
    }
    for (; i < end; i += 256) {
        unsigned v4 = binned[i];
        int d = (int)((v4 >> 16) & 0xffu);
        int k = atomicAdd(&loff[d], 1);
        rec4[lstart[d] + k] = (int)(v4 & 0xffffu);
    }
}

// ---------------- gather-side aggregation, v3 ----------------
// Wave = 1 node. Lane L: g = L>>3 (8 edge slots), q = L&7 (8 bf16 = 16B per lane).
// Per 64-edge chunk: cooperative (src,w) preload + shfl broadcast; loads and FMA in
// two statically-indexed unrolled loops -> up to 8 gathers in flight per wave.

#define ACC8(hv, wt)                                                   \
    acc[0] = fmaf(__uint_as_float((hv).x << 16),         wt, acc[0]);  \
    acc[1] = fmaf(__uint_as_float((hv).x & 0xffff0000u), wt, acc[1]);  \
    acc[2] = fmaf(__uint_as_float((hv).y << 16),         wt, acc[2]);  \
    acc[3] = fmaf(__uint_as_float((hv).y & 0xffff0000u), wt, acc[3]);  \
    acc[4] = fmaf(__uint_as_float((hv).z << 16),         wt, acc[4]);  \
    acc[5] = fmaf(__uint_as_float((hv).z & 0xffff0000u), wt, acc[5]);  \
    acc[6] = fmaf(__uint_as_float((hv).w << 16),         wt, acc[6]);  \
    acc[7] = fmaf(__uint_as_float((hv).w & 0xffff0000u), wt, acc[7]);

#define GATHER_CHUNK(OFFS)                                                     \
    for (int c0 = 0; c0 < n; c0 += 64) {                                       \
        int idx_l = c0 + L;                                                    \
        int sreg = node;                                                       \
        float wreg = 0.f;                                                      \
        if (idx_l < n) {                                                       \
            sreg = rec4[beg + idx_l];                                          \
            wreg = dinv[sreg] * dvd;                                           \
        }                                                                      \
        int m = n - c0; if (m > 64) m = 64;                                    \
        int umax = (m + 7) >> 3;                                               \
        uint4 hv[8];                                                           \
        _Pragma("unroll")                                                      \
        for (int u = 0; u < 8; ++u) {                                          \
            if (u < umax) {                                                    \
                int sidx = __shfl(sreg, u * 8 + g, 64);                        \
                hv[u] = *(const uint4*)(hb + (size_t)sidx * 256 + (OFFS) + q * 8); \
            }                                                                  \
        }                                                                      \
        _Pragma("unroll")                                                      \
        for (int u = 0; u < 8; ++u) {                                          \
            if (u < umax) {                                                    \
                float wt = __shfl(wreg, u * 8 + g, 64);                        \
                ACC8(hv[u], wt)                                                \
            }                                                                  \
        }                                                                      \
    }

// layer 1: gather bf16 h1 (ushort cols [128..191]); write bf16 hrelu = relu(acc + dv^2*own + b1)
__global__ void gather_relu_kernel(const int* __restrict__ rec4, const int* __restrict__ row_start,
                                   const int* __restrict__ cnt, const float* __restrict__ dinv,
                                   const float* __restrict__ b1, float* __restrict__ out, int N) {
    int node = blockIdx.x * 4 + (threadIdx.x >> 6);
    if (node >= N) return;
    int L = threadIdx.x & 63;
    int g = L >> 3;
    int q = L & 7;
    const ushort* hb = (const ushort*)out;
    int beg = row_start[node];
    int n   = cnt[node];
    float dvd = dinv[node];
    float acc[8] = {0.f, 0.f, 0.f, 0.f, 0.f, 0.f, 0.f, 0.f};
    GATHER_CHUNK(128)
    #pragma unroll
    for (int off = 8; off < 64; off <<= 1)
        #pragma unroll
        for (int j = 0; j < 8; ++j)
            acc[j] += __shfl_xor(acc[j], off, 64);
    if (L < 8) {
        float dv2 = dvd * dvd;
        uint4 ho = *(const uint4*)(hb + (size_t)node * 256 + 128 + q * 8);
        float4 bl = *(const float4*)&b1[q * 8];
        float4 bh = *(const float4*)&b1[q * 8 + 4];
        float r0 = fmaxf(acc[0] + dv2 * __uint_as_float(ho.x << 16)         + bl.x, 0.f);
        float r1 = fmaxf(acc[1] + dv2 * __uint_as_float(ho.x & 0xffff0000u) + bl.y, 0.f);
        float r2 = fmaxf(acc[2] + dv2 * __uint_as_float(ho.y << 16)         + bl.z, 0.f);
        float r3 = fmaxf(acc[3] + dv2 * __uint_as_float(ho.y & 0xffff0000u) + bl.w, 0.f);
        float r4 = fmaxf(acc[4] + dv2 * __uint_as_float(ho.z << 16)         + bh.x, 0.f);
        float r5 = fmaxf(acc[5] + dv2 * __uint_as_float(ho.z & 0xffff0000u) + bh.y, 0.f);
        float r6 = fmaxf(acc[6] + dv2 * __uint_as_float(ho.w << 16)         + bh.z, 0.f);
        float r7 = fmaxf(acc[7] + dv2 * __uint_as_float(ho.w & 0xffff0000u) + bh.w, 0.f);
        uint4 st;
        st.x = (unsigned)f2bf(r0) | ((unsigned)f2bf(r1) << 16);
        st.y = (unsigned)f2bf(r2) | ((unsigned)f2bf(r3) << 16);
        st.z = (unsigned)f2bf(r4) | ((unsigned)f2bf(r5) << 16);
        st.w = (unsigned)f2bf(r6) | ((unsigned)f2bf(r7) << 16);
        *(uint4*)((ushort*)out + (size_t)node * 256 + 192 + q * 8) = st;
    }
}

// layer 2: gather bf16 hrelu (ushort cols [192..255]); write fp32 combined to float[0..63]
__global__ void gather_comb_kernel(const int* __restrict__ rec4, const int* __restrict__ row_start,
                                   const int* __restrict__ cnt, const float* __restrict__ dinv,
                                   float* __restrict__ out, int N) {
    int node = blockIdx.x * 4 + (threadIdx.x >> 6);
    if (node >= N) return;
    int L = threadIdx.x & 63;
    int g = L >> 3;
    int q = L & 7;
    const ushort* hb = (const ushort*)out;
    int beg = row_start[node];
    int n   = cnt[node];
    float dvd = dinv[node];
    float acc[8] = {0.f, 0.f, 0.f, 0.f, 0.f, 0.f, 0.f, 0.f};
    GATHER_CHUNK(192)
    #pragma unroll
    for (int off = 8; off < 64; off <<= 1)
        #pragma unroll
        for (int j = 0; j < 8; ++j)
            acc[j] += __shfl_xor(acc[j], off, 64);
    if (L < 8) {
        float dv2 = dvd * dvd;
        uint4 ho = *(const uint4*)(hb + (size_t)node * 256 + 192 + q * 8);
        float4 o0, o1;
        o0.x = acc[0] + dv2 * __uint_as_float(ho.x << 16);
        o0.y = acc[1] + dv2 * __uint_as_float(ho.x & 0xffff0000u);
        o0.z = acc[2] + dv2 * __uint_as_float(ho.y << 16);
        o0.w = acc[3] + dv2 * __uint_as_float(ho.y & 0xffff0000u);
        o1.x = acc[4] + dv2 * __uint_as_float(ho.z << 16);
        o1.y = acc[5] + dv2 * __uint_as_float(ho.z & 0xffff0000u);
        o1.z = acc[6] + dv2 * __uint_as_float(ho.w << 16);
        o1.w = acc[7] + dv2 * __uint_as_float(ho.w & 0xffff0000u);
        *(float4*)&out[(size_t)node * FO + q * 8]     = o0;
        *(float4*)&out[(size_t)node * FO + q * 8 + 4] = o1;
    }
}

// ---------------- dense kernels ----------------

// fallback mm1 (LDS-staged, r8/r9-validated) — workspace-free path only.
__global__ __launch_bounds__(512) void mm1_mfma(const float* __restrict__ x,
                                                const float* __restrict__ W1,
                                                float* __restrict__ out, int N) {
    __shared__ short bfH[2048 * 8];
    __shared__ short bfL[2048 * 8];
    int tid = threadIdx.x;
    #pragma unroll
    for (int i = 0; i < 8; ++i) {
        int f = i * 512 + tid;
        float4 wv = *(const float4*)&W1[(size_t)f * 4];
        int k  = f >> 4;
        int c4 = f & 15;
        int j  = k & 7;
        int e0 = ((c4 >> 2) * 8 + (k >> 5)) * 64 + ((k >> 3) & 3) * 16 + (c4 & 3) * 4;
        float vv[4] = {wv.x, wv.y, wv.z, wv.w};
        #pragma unroll
        for (int cc = 0; cc < 4; ++cc) {
            ushort h = f2bf(vv[cc]);
            bfH[(e0 + cc) * 8 + j] = (short)h;
            bfL[(e0 + cc) * 8 + j] = (short)f2bf(vv[cc] - bf2f(h));
        }
    }
    __syncthreads();
    int wid = tid >> 6;
    int l   = tid & 63;
    int R0  = blockIdx.x * 128;
    int rowA = R0 + wid * 16 + (l & 15);
    int kg   = l >> 4;
    const float* xr = x + (size_t)rowA * FI;
    bool ok = rowA < N;
    const float4 z4 = make_float4(0.f, 0.f, 0.f, 0.f);
    f32x4 acc[4];
    #pragma unroll
    for (int c = 0; c < 4; ++c) acc[c] = (f32x4){0.f, 0.f, 0.f, 0.f};
    float4 xa = ok ? *(const float4*)&xr[kg * 8]     : z4;
    float4 xb = ok ? *(const float4*)&xr[kg * 8 + 4] : z4;
    #pragma unroll
    for (int t = 0; t < 8; ++t) {
        bf16x8 ah, al;
        {
            float va[8] = {xa.x, xa.y, xa.z, xa.w, xb.x, xb.y, xb.z, xb.w};
            #pragma unroll
            for (int j = 0; j < 8; ++j) {
                ushort h = f2bf(va[j]);
                ah[j] = (short)h;
                al[j] = (short)f2bf(va[j] - bf2f(h));
            }
        }
        if (t < 7) {
            int kb = (t + 1) * 32 + kg * 8;
            xa = ok ? *(const float4*)&xr[kb]     : z4;
            xb = ok ? *(const float4*)&xr[kb + 4] : z4;
        }
        #pragma unroll
        for (int c = 0; c < 4; ++c) {
            int e = (c * 8 + t) * 64 + l;
            bf16x8 bh = *(const bf16x8*)&bfH[e * 8];
            bf16x8 bl = *(const bf16x8*)&bfL[e * 8];
            acc[c] = __builtin_amdgcn_mfma_f32_16x16x32_bf16(ah, bh, acc[c], 0, 0, 0);
            acc[c] = __builtin_amdgcn_mfma_f32_16x16x32_bf16(ah, bl, acc[c], 0, 0, 0);
            acc[c] = __builtin_amdgcn_mfma_f32_16x16x32_bf16(al, bh, acc[c], 0, 0, 0);
        }
    }
    {
        int rbase = R0 + wid * 16 + (l >> 4) * 4;
        #pragma unroll
        for (int r = 0; r < 4; ++r) {
            int row = rbase + r;
            if (row < N) {
                ushort* ob = (ushort*)out + (size_t)row * 256 + 128;
                #pragma unroll
                for (int c = 0; c < 4; ++c)
                    ob[c * 16 + (l & 15)] = f2bf(acc[c][r]);
            }
        }
    }
}

// mm2: out_row = combined(float[0..63]) @ W2 + b2, in place.
__global__ __launch_bounds__(256) void mm2_tiled(const float* __restrict__ W2,
                                                 const float* __restrict__ b2,
                                                 float* __restrict__ out, int N) {
    __shared__ float xs[64][68];
    __shared__ float ws[64][128];
    int tid = threadIdx.x;
    int R0  = blockIdx.x * 64;
    int ty  = tid >> 4;
    int tx  = tid & 15;

    {
        int sr = tid >> 2;
        int l4 = tid & 3;
        int grow = R0 + sr;
        bool ok = grow < N;
        const float* orow = out + (size_t)grow * FO;
        #pragma unroll
        for (int q = 0; q < 4; ++q) {
            int j0 = (l4 + 4 * q) * 4;
            float4 a = ok ? *(const float4*)&orow[j0] : make_float4(0.f, 0.f, 0.f, 0.f);
            xs[j0 + 0][sr] = a.x;
            xs[j0 + 1][sr] = a.y;
            xs[j0 + 2][sr] = a.z;
            xs[j0 + 3][sr] = a.w;
        }
    }
    #pragma unroll
    for (int q = 0; q < 8; ++q) {
        int f = tid + q * 256;
        *(float4*)&ws[f >> 5][(f & 31) * 4] = *(const float4*)&W2[(size_t)f * 4];
    }
    __syncthreads();

    float acc[4][8];
    #pragma unroll
    for (int i = 0; i < 4; ++i)
        #pragma unroll
        for (int j = 0; j < 8; ++j) acc[i][j] = 0.f;

    #pragma unroll 4
    for (int k = 0; k < FH; ++k) {
        float4 a  = *(const float4*)&xs[k][ty * 4];
        float4 bl = *(const float4*)&ws[k][tx * 4];
        float4 bh = *(const float4*)&ws[k][64 + tx * 4];
        float av[4] = {a.x, a.y, a.z, a.w};
        float bv[8] = {bl.x, bl.y, bl.z, bl.w, bh.x, bh.y, bh.z, bh.w};
        #pragma unroll
        for (int i = 0; i < 4; ++i)
            #pragma unroll
            for (int j = 0; j < 8; ++j)
                acc[i][j] = fmaf(av[i], bv[j], acc[i][j]);
    }

    float4 b2l = *(const float4*)&b2[tx * 4];
    float4 b2h = *(const float4*)&b2[64 + tx * 4];
    #pragma unroll
    for (int i = 0; i < 4; ++i) {
        int row = R0 + ty * 4 + i;
        if (row < N) {
            float* o = out + (size_t)row * FO;
            *(float4*)&o[tx * 4] = make_float4(acc[i][0] + b2l.x, acc[i][1] + b2l.y,
                                               acc[i][2] + b2l.z, acc[i][3] + b2l.w);
            *(float4*)&o[64 + tx * 4] = make_float4(acc[i][4] + b2h.x, acc[i][5] + b2h.y,
                                                    acc[i][6] + b2h.z, acc[i][7] + b2h.w);
        }
    }
}

// ---------------- fallback (atomic scatter) pieces — all fp32 ----------------

__global__ void expand_hs1_kernel(float* __restrict__ out, int N) {
    int row = blockIdx.x * 4 + (threadIdx.x >> 6);
    if (row >= N) return;
    int lane = threadIdx.x & 63;
    float v = bf2f(((const ushort*)out)[(size_t)row * 256 + 128 + lane]);
    out[(size_t)row * FO + FH + lane] = v;
}

__global__ void zero_half_kernel(float* __restrict__ out, int half, int N) {
    int i = blockIdx.x * 256 + threadIdx.x;
    if (i >= N * FH) return;
    out[(size_t)(i >> 6) * FO + half + (i & 63)] = 0.f;
}

__global__ void scatter_half_kernel(const int* __restrict__ src, const int* __restrict__ dst,
                                    const float* __restrict__ dinv, float* __restrict__ out,
                                    int rh, int wh, int E) {
    int e = blockIdx.x * 4 + (threadIdx.x >> 6);
    if (e >= E) return;
    int lane = threadIdx.x & 63;
    int s = src[e];
    int d = dst[e];
    float w = dinv[s] * dinv[d];
    atomicAdd(&out[(size_t)d * FO + wh + lane], out[(size_t)s * FO + rh + lane] * w);
}

// lower = relu(lower_agg + dv^2*upper_own + b1)
__global__ void finish1_kernel(float* __restrict__ out, const float* __restrict__ dinv,
                               const float* __restrict__ b1, int N) {
    int i = blockIdx.x * 256 + threadIdx.x;
    if (i >= N * FH) return;
    int row = i >> 6;
    int c   = i & 63;
    size_t base = (size_t)row * FO;
    float dv = dinv[row];
    out[base + c] = fmaxf(out[base + c] + dv * dv * out[base + FH + c] + b1[c], 0.f);
}

// lower = upper_agg + dv^2*lower_own   (combined for mm2)
__global__ void finish2_kernel(float* __restrict__ out, const float* __restrict__ dinv, int N) {
    int i = blockIdx.x * 256 + threadIdx.x;
    if (i >= N * FH) return;
    int row = i >> 6;
    int c   = i & 63;
    size_t base = (size_t)row * FO;
    float dv = dinv[row];
    out[base + c] = out[base + FH + c] + dv * dv * out[base + c];
}

extern "C" void kernel_launch(void* const* d_in, const int* in_sizes, int n_in,
                              void* d_out, int out_size, void* d_ws, size_t ws_size,
                              hipStream_t stream) {
    const float* x  = (const float*)d_in[0];
    const int*   ei = (const int*)d_in[1];
    const float* W1 = (const float*)d_in[2];
    const float* b1 = (const float*)d_in[3];
    const float* W2 = (const float*)d_in[4];
    const float* b2 = (const float*)d_in[5];
    float* out = (float*)d_out;

    int N = in_sizes[0] / FI;     // 50000
    int E = in_sizes[1] / 2;      // 1600000
    const int* src = ei;
    const int* dst = ei + E;

    char* w = (char*)d_ws;
    float* dinv        = (float*)w;      w += (size_t)N * 4;
    int*   cnt         = (int*)w;        w += (size_t)N * 4;
    int*   row_start   = (int*)w;        w += (size_t)N * 4;
    int*   bucket_cnt  = (int*)w;        w += 256 * 4;
    int*   bucket_pos  = (int*)w;        w += 256 * 4;
    int*   bucket_base = (int*)w;        w += 260 * 4;
    short* wfragH      = (short*)w;      w += 2048 * 8 * 2;   // 32KB
    short* wfragL      = (short*)w;      w += 2048 * 8 * 2;   // 32KB
    unsigned* binned   = (unsigned*)w;   w += (size_t)E * 4;
    int*   rec4        = (int*)w;        w += (size_t)E * 4;
    size_t need = (size_t)(w - (char*)d_ws);   // ~13.5 MB

    int nblkA = (E + ASORT_CHUNK - 1) / ASORT_CHUNK;   // 782
    int nmm1  = (N + 63) / 64;                         // 782
    int nbk   = (N + 255) >> 8;                        // 196 buckets for N=50000

    if (ws_size >= need && N <= 65536) {
        zero_i32<<<1, 256, 0, stream>>>(bucket_cnt, 256);
        hist_wprep_kernel<<<nblkA + 16, 256, 0, stream>>>(dst, bucket_cnt, W1, wfragH, wfragL, E, nblkA);
        bucket_scan_kernel<<<1, 256, 0, stream>>>(bucket_cnt, bucket_base, bucket_pos, E);
        binA_mm1_kernel<<<nblkA + nmm1, 256, 0, stream>>>(src, dst, bucket_pos, binned, E,
                                                          x, wfragH, wfragL, out, N, nblkA);
        binB_kernel<<<nbk, 256, 0, stream>>>(bucket_base, binned, rec4, row_start, cnt, dinv, N);

        gather_relu_kernel<<<(N + 3) / 4, 256, 0, stream>>>(rec4, row_start, cnt, dinv, b1, out, N);
        gather_comb_kernel<<<(N + 3) / 4, 256, 0, stream>>>(rec4, row_start, cnt, dinv, out, N);
        mm2_tiled<<<(N + 63) / 64, 256, 0, stream>>>(W2, b2, out, N);
    } else {
        // fallback: atomic scatter path, all fp32 (LDS-staged mm1)
        zero_i32<<<(N + 255) / 256, 256, 0, stream>>>(cnt, N);
        deg_cnt_kernel<<<(E + 1023) / 1024, 256, 0, stream>>>(dst, cnt, E);
        dinv_kernel<<<(N + 255) / 256, 256, 0, stream>>>(cnt, dinv, N);
        mm1_mfma<<<(N + 127) / 128, 512, 0, stream>>>(x, W1, out, N);
        expand_hs1_kernel<<<(N + 3) / 4, 256, 0, stream>>>(out, N);
        zero_half_kernel<<<((N * FH) + 255) / 256, 256, 0, stream>>>(out, 0, N);
        scatter_half_kernel<<<(E + 3) / 4, 256, 0, stream>>>(src, dst, dinv, out, FH, 0, E);
        finish1_kernel<<<((N * FH) + 255) / 256, 256, 0, stream>>>(out, dinv, b1, N);
        zero_half_kernel<<<((N * FH) + 255) / 256, 256, 0, stream>>>(out, FH, N);
        scatter_half_kernel<<<(E + 3) / 4, 256, 0, stream>>>(src, dst, dinv, out, 0, FH, E);
        finish2_kernel<<<((N * FH) + 255) / 256, 256, 0, stream>>>(out, dinv, N);
        mm2_tiled<<<(N + 63) / 64, 256, 0, stream>>>(W2, b2, out, N);
    }
}